// Round 12
// baseline (776.483 us; speedup 1.0000x reference)
//
#include <hip/hip_runtime.h>
#include <hip/hip_bf16.h>

#define BB 8
#define NN 2048
#define KK 20
#define BBNN (BB * NN)

typedef __hip_bfloat16 bf16;
typedef unsigned short u16;
typedef __attribute__((ext_vector_type(8))) short short8;
typedef __attribute__((ext_vector_type(4))) float f32x4;

__device__ __forceinline__ float b2f(bf16 v) { return __bfloat162float(v); }

// ---------------------------------------------------------------- sq + transpose (fused)
template<int C>
__global__ __launch_bounds__(256) void sqT_kernel(const float* __restrict__ xin,
                                                  float* __restrict__ sq,
                                                  float* __restrict__ xT) {
    int t = blockIdx.x * 256 + threadIdx.x;
    if (t >= BBNN) return;
    const float* p = xin + (size_t)t * C;
    float s = 0.f;
    for (int c = 0; c < C; ++c) {
        float v = p[c];
        s += v * v;
        xT[(size_t)c * BBNN + t] = v;
    }
    sq[t] = s;
}

// ---------------------------------------------------------------- single-query selection (shared)
// v12 selection semantics: per-lane top-2 cache + removal bitmask + 64-lane
// lexicographic argmin butterfly. Branch-free owner update (cndmask).
// Live set ~50 regs -> proven spill-free in knn1 (round 11).
__device__ __forceinline__ void select_topk(const float d[32], int s, int base_out,
                                            u16* __restrict__ idx_out) {
    unsigned rm = 0u;
    float m1 = INFINITY, m2 = INFINITY;
    int j1 = 0x7fffffff, j2 = 0x7fffffff;
    #pragma unroll
    for (int r = 0; r < 32; ++r) {
        int j = ((r >> 2) << 8) + (s << 2) + (r & 3);
        float v = d[r];
        bool l1 = v < m1, l2 = v < m2;
        m2 = l1 ? m1 : (l2 ? v : m2);
        j2 = l1 ? j1 : (l2 ? j : j2);
        m1 = l1 ? v : m1;  j1 = l1 ? j : j1;
    }
    for (int k = 0; k < KK; ++k) {
        if (__any(j1 < 0)) {
            if (j1 < 0) {
                m1 = INFINITY; m2 = INFINITY; j1 = 0x7fffffff; j2 = 0x7fffffff;
                #pragma unroll
                for (int r = 0; r < 32; ++r) {
                    int j = ((r >> 2) << 8) + (s << 2) + (r & 3);
                    float v = (rm & (1u << r)) ? INFINITY : d[r];
                    bool l1 = v < m1, l2 = v < m2;
                    m2 = l1 ? m1 : (l2 ? v : m2);
                    j2 = l1 ? j1 : (l2 ? j : j2);
                    m1 = l1 ? v : m1;  j1 = l1 ? j : j1;
                }
            }
        }
        float rd = m1; int rj = j1;
        #pragma unroll
        for (int m = 1; m < 64; m <<= 1) {
            float od = __shfl_xor(rd, m); int oj = __shfl_xor(rj, m);
            if (od < rd || (od == rd && oj < rj)) { rd = od; rj = oj; }
        }
        if (s == 0) idx_out[(size_t)base_out * KK + k] = (u16)rj;
        if (k + 1 < KK) {
            // branch-free owner update
            bool won = (s == ((rj >> 2) & 63));
            int rr = ((rj >> 8) << 2) + (rj & 3);
            rm |= won ? (1u << rr) : 0u;
            m1 = won ? m2 : m1;
            j1 = won ? j2 : j1;
            m2 = won ? INFINITY : m2;
            j2 = won ? -1 : j2;
        }
    }
}

// ---------------------------------------------------------------- kNN, 1 query/wave (for C=3)
template<int C>
__global__ __launch_bounds__(512, 4) void knn1_kernel(
        const float* __restrict__ xrows,
        const float* __restrict__ xT,
        const float* __restrict__ sq,
        u16* __restrict__ idx_out) {
    __shared__ __align__(16) float xs[C][2048];
    const int blk = blockIdx.x;            // BB * 256
    const int b = blk >> 8;
    const int tile = blk & 255;
    const int w = threadIdx.x >> 6;
    const int s = threadIdx.x & 63;
    const int tid = threadIdx.x;
    const int iA = tile * 8 + w;
    const int bn0 = b * NN;

    float dA[32];
    #pragma unroll
    for (int r = 0; r < 32; ++r) dA[r] = 0.f;

    for (int u = tid; u < C * 512; u += 512) {
        int row = u / 512, c4 = u % 512;
        *(float4*)&xs[row][c4 * 4] =
            *(const float4*)(xT + (size_t)row * BBNN + bn0 + c4 * 4);
    }
    __syncthreads();

    const int qbase = __builtin_amdgcn_readfirstlane((bn0 + iA) * C);
    float xq[C];
    #pragma unroll
    for (int cc = 0; cc < C; ++cc) xq[cc] = xrows[qbase + cc];

    #pragma unroll
    for (int t = 0; t < 8; ++t) {
        float a0 = 0.f, a1 = 0.f, a2 = 0.f, a3 = 0.f;
        #pragma unroll
        for (int cc = 0; cc < C; ++cc) {
            float4 xv = *(const float4*)&xs[cc][t * 256 + s * 4];
            float q = xq[cc];
            a0 += q * xv.x; a1 += q * xv.y; a2 += q * xv.z; a3 += q * xv.w;
        }
        dA[t * 4 + 0] += a0; dA[t * 4 + 1] += a1;
        dA[t * 4 + 2] += a2; dA[t * 4 + 3] += a3;
    }
    const float sqi = sq[bn0 + iA];
    #pragma unroll
    for (int r = 0; r < 32; ++r) {
        int j = ((r >> 2) << 8) + (s << 2) + (r & 3);
        dA[r] = (sqi + sq[bn0 + j]) - 2.f * dA[r];
    }
    select_topk(dA, s, bn0 + iA, idx_out);
}

// ---------------------------------------------------------------- fast kNN v15 (C=64)
// v12 post-mortem chain: interleaved A/B selection keeps 64 accumulators +
// 2x state live through the 20-iteration ballot k-loop -> RA splits/spills
// (VGPR_Count=64 + 53.9MB scratch). knn1 (round 11) proved the SAME selection
// with a single query's live set (~50 regs) compiles spill-free.
// v15: SEQUENTIAL selection. A's full selection runs with dB parked (written
// once per chunk, untouched -> allocator shelves it in AGPRs with no k-loop
// round-trips); then B's selection with dA dead. Branch-free owner update.
// Distance phase identical to v12; output semantics identical.
template<int C, int CH>
__global__ __launch_bounds__(512, 4) void knn_fast_kernel(
        const float* __restrict__ xrows,
        const float* __restrict__ xT,
        const float* __restrict__ sq,
        u16* __restrict__ idx_out) {
    __shared__ __align__(16) float xs[CH][2048];
    const int blk = blockIdx.x;            // BB * 128
    const int b = blk >> 7;
    const int tile = blk & 127;
    const int w = threadIdx.x >> 6;
    const int s = threadIdx.x & 63;
    const int iA = tile * 16 + w * 2;
    const int bn0 = b * NN;
    constexpr int NCH = C / CH;            // 8 for <64,8>

    float dA[32], dB[32];
    #pragma unroll
    for (int r = 0; r < 32; ++r) { dA[r] = 0.f; dB[r] = 0.f; }

    const int qbase = __builtin_amdgcn_readfirstlane((bn0 + iA) * C);

    for (int ch = 0; ch < NCH; ++ch) {
        __syncthreads();   // WAR guard vs previous phase's readers
        for (int u = threadIdx.x; u < CH * 512; u += 512) {
            int row = u >> 9, c4 = u & 511;
            *(float4*)&xs[row][c4 * 4] =
                *(const float4*)(xT + (size_t)(ch * CH + row) * BBNN + bn0 + c4 * 4);
        }
        __syncthreads();
        float xqA[CH], xqB[CH];            // wave-uniform -> scalar loads
        #pragma unroll
        for (int cc = 0; cc < CH; ++cc) {
            xqA[cc] = xrows[qbase + ch * CH + cc];
            xqB[cc] = xrows[qbase + C + ch * CH + cc];
        }
        #pragma unroll
        for (int t = 0; t < 8; ++t) {      // unrolled -> dA/dB indices static
            float aA0 = 0.f, aA1 = 0.f, aA2 = 0.f, aA3 = 0.f;
            float aB0 = 0.f, aB1 = 0.f, aB2 = 0.f, aB3 = 0.f;
            #pragma unroll
            for (int cc = 0; cc < CH; ++cc) {
                float4 xv = *(const float4*)&xs[cc][t * 256 + s * 4];
                float qA = xqA[cc], qB = xqB[cc];
                aA0 += qA * xv.x; aA1 += qA * xv.y; aA2 += qA * xv.z; aA3 += qA * xv.w;
                aB0 += qB * xv.x; aB1 += qB * xv.y; aB2 += qB * xv.z; aB3 += qB * xv.w;
            }
            dA[t * 4 + 0] += aA0; dA[t * 4 + 1] += aA1;
            dA[t * 4 + 2] += aA2; dA[t * 4 + 3] += aA3;
            dB[t * 4 + 0] += aB0; dB[t * 4 + 1] += aB1;
            dB[t * 4 + 2] += aB2; dB[t * 4 + 3] += aB3;
        }
    }
    const float sqiA = sq[bn0 + iA];
    const float sqiB = sq[bn0 + iA + 1];
    #pragma unroll
    for (int r = 0; r < 32; ++r) {
        int j = ((r >> 2) << 8) + (s << 2) + (r & 3);
        float sqj = sq[bn0 + j];
        dA[r] = (sqiA + sqj) - 2.f * dA[r];
        dB[r] = (sqiB + sqj) - 2.f * dB[r];
    }

    // sequential: A's full selection (dB parked), then B's (dA dead)
    select_topk(dA, s, bn0 + iA, idx_out);
    select_topk(dB, s, bn0 + iA + 1, idx_out);
}

// ---------------------------------------------------------------- G[n][h] = x[n] . w1_lower[.][h]
// w1 row-major [2*CIN][64]; lower half = rows CIN..2CIN-1 (the (xj-xi) part).
template<int CIN>
__global__ __launch_bounds__(256) void gemmG_kernel(const float* __restrict__ xin,
                                                    const float* __restrict__ w1,
                                                    float* __restrict__ G) {
    __shared__ float wls[CIN * 64];
    __shared__ float xr[4][CIN];
    const int bn0 = blockIdx.x * 4;
    const int tid = threadIdx.x;
    for (int p = tid; p < CIN * 64; p += 256) wls[p] = w1[CIN * 64 + p];
    for (int p = tid; p < 4 * CIN; p += 256)
        xr[p / CIN][p % CIN] = xin[(size_t)bn0 * CIN + p];
    __syncthreads();
    const int pp = tid >> 6, h = tid & 63;
    float a = 0.f;
    for (int c = 0; c < CIN; ++c) a += xr[pp][c] * wls[c * 64 + h];
    G[(size_t)(bn0 + pp) * 64 + h] = a;
}

// ---------------------------------------------------------------- EdgeConv v3: G-decomposed
// 4 points/block. Layer1 per edge = gather G[j] + add (no MACs):
//   h1[k][h] = relu( (b1[h] + xi.W1u[h] - G[i][h]) + G[j][h] )   [algebraically
//   identical to relu(b1 + xi.W1u + (xj-xi).W1l); fp reorder only]
// Layer2: thread owns output column o; W2 column held in 64 VGPRs (loaded once
// from global, L2-resident) -> pure v_fmac_f32 with h1 float4 LDS broadcasts.
template<int CIN, int COUT, bool BF16OUT>
__global__ __launch_bounds__(256) void edgeconv3_kernel(
        const float* __restrict__ xin, const u16* __restrict__ knn,
        const float* __restrict__ w1, const float* __restrict__ b1,
        const float* __restrict__ w2, const float* __restrict__ b2,
        const float* __restrict__ G, void* __restrict__ out) {
    constexpr int SPLIT = 256 / COUT;      // 2 for COUT=128, 4 for COUT=64
    constexpr int KPS = KK / SPLIT;        // 10 / 5
    const int bn0 = blockIdx.x * 4;
    const int b = bn0 >> 11;
    const int tid = threadIdx.x;
    __shared__ float w1us[CIN * 64];                   // upper half (xi part)
    __shared__ float xr[4][CIN];
    __shared__ __align__(16) float h1s[4][KK][64];
    __shared__ float pms[4][SPLIT][COUT];
    __shared__ int js[4][KK];

    for (int p = tid; p < CIN * 64; p += 256) w1us[p] = w1[p];
    for (int p = tid; p < 4 * CIN; p += 256)
        xr[p / CIN][p % CIN] = xin[(size_t)bn0 * CIN + p];
    if (tid < 4 * KK) {
        int j = knn[(size_t)(bn0 + tid / KK) * KK + (tid % KK)];
        js[tid / KK][tid % KK] = (j < NN) ? j : 0;
    }
    __syncthreads();

    // phase 1: h1[pp][k][h]
    {
        const int pp = tid >> 6, h = tid & 63;
        float u = b1[h];
        for (int c = 0; c < CIN; ++c) u += xr[pp][c] * w1us[c * 64 + h];
        u -= G[(size_t)(bn0 + pp) * 64 + h];
        const float* Gb = G + (size_t)b * NN * 64 + h;
        for (int k = 0; k < KK; ++k) {
            float gj = Gb[(size_t)js[pp][k] * 64];
            h1s[pp][k][h] = fmaxf(u + gj, 0.f);
        }
    }
    __syncthreads();

    // phase 2: layer2, W2 column in registers
    {
        const int o = tid % COUT, ks = tid / COUT;
        float wcol[64];
        #pragma unroll
        for (int c = 0; c < 64; ++c) wcol[c] = w2[c * COUT + o];
        #pragma unroll
        for (int pp = 0; pp < 4; ++pp) {
            float mx = -INFINITY;
            for (int k = ks * KPS; k < (ks + 1) * KPS; ++k) {
                float acc = 0.f;
                #pragma unroll
                for (int c4 = 0; c4 < 16; ++c4) {
                    float4 hv = *(const float4*)&h1s[pp][k][c4 * 4];
                    acc += hv.x * wcol[c4 * 4 + 0];
                    acc += hv.y * wcol[c4 * 4 + 1];
                    acc += hv.z * wcol[c4 * 4 + 2];
                    acc += hv.w * wcol[c4 * 4 + 3];
                }
                mx = fmaxf(mx, acc);
            }
            pms[pp][ks][o] = mx;
        }
    }
    __syncthreads();
    for (int idx = tid; idx < 4 * COUT; idx += 256) {
        int pp = idx / COUT, oo = idx % COUT;
        float mx = pms[pp][0][oo];
        #pragma unroll
        for (int s2 = 1; s2 < SPLIT; ++s2) mx = fmaxf(mx, pms[pp][s2][oo]);
        mx += b2[oo];
        if (BF16OUT) ((bf16*)out)[(size_t)(bn0 + pp) * COUT + oo] = __float2bfloat16(mx);
        else         ((float*)out)[(size_t)(bn0 + pp) * COUT + oo] = mx;
    }
}

// ---------------------------------------------------------------- global max over N (2-stage)
__global__ __launch_bounds__(128) void gmax1_kernel(const bf16* __restrict__ f2,
                                                    float* __restrict__ pmax) {
    const int b = blockIdx.x >> 4, ch = blockIdx.x & 15, c = threadIdx.x;
    float m = -INFINITY;
    const bf16* base = f2 + ((size_t)(b * NN + ch * 128)) * 128 + c;
    for (int n = 0; n < 128; ++n) m = fmaxf(m, b2f(base[(size_t)n * 128]));
    pmax[blockIdx.x * 128 + c] = m;
}

__global__ __launch_bounds__(128) void gmax2_kernel(const float* __restrict__ pmax,
                                                    float* __restrict__ glob) {
    const int b = blockIdx.x, c = threadIdx.x;
    float m = -INFINITY;
    for (int ch = 0; ch < 16; ++ch) m = fmaxf(m, pmax[(b * 16 + ch) * 128 + c]);
    glob[b * 128 + c] = m;
}

// ---------------------------------------------------------------- K + V^T for all heads
__global__ __launch_bounds__(256) void kvt_kernel(const bf16* __restrict__ f2,
                                                  const float* __restrict__ qkv_w,
                                                  bf16* __restrict__ kk,
                                                  bf16* __restrict__ vt) {
    const int blk = blockIdx.x;
    const int h = blk >> 12;
    const int rg = blk & 4095;
    const int bn0 = rg * 4;
    const int b = bn0 >> 11, n0 = bn0 & 2047;
    const int tid = threadIdx.x;
    __shared__ float Ws[2][128][32];
    __shared__ float f2s[4][128];
    __shared__ float vbuf[4][32];
    for (int p = tid; p < 2 * 128 * 32; p += 256) {
        int kv = p >> 12, c = (p >> 5) & 127, d = p & 31;
        Ws[kv][c][d] = qkv_w[c * 384 + 128 + kv * 128 + h * 32 + d];
    }
    for (int p = tid; p < 4 * 128; p += 256) {
        int rr = p >> 7, c = p & 127;
        f2s[rr][c] = b2f(f2[(size_t)(bn0 + rr) * 128 + c]);
    }
    __syncthreads();
    const int rr = tid >> 6, u = tid & 63, kv = u >> 5, d = u & 31;
    float acc = 0.f;
    for (int c = 0; c < 128; ++c) acc += f2s[rr][c] * Ws[kv][c][d];
    if (kv == 0)
        kk[((size_t)(b * 4 + h) * 2048 + n0 + rr) * 32 + d] = __float2bfloat16(acc);
    else
        vbuf[rr][d] = acc;
    __syncthreads();
    if (tid < 128) {
        int dd = tid >> 2, r2 = tid & 3;
        vt[((size_t)(b * 4 + h) * 32 + dd) * 2048 + n0 + r2] = __float2bfloat16(vbuf[r2][dd]);
    }
}

// ---------------------------------------------------------------- MFMA flash attention
__global__ __launch_bounds__(256) void attn_mfma_kernel(
        const bf16* __restrict__ f2, const float* __restrict__ qkv_w,
        const bf16* __restrict__ kk, const bf16* __restrict__ vt,
        bf16* __restrict__ atth) {
    const int blk = blockIdx.x;
    const int tile = blk & 31;
    const int h = (blk >> 5) & 3;
    const int b = blk >> 7;
    const int tid = threadIdx.x;
    const int w = tid >> 6;
    const int lane = tid & 63;
    const int lq = lane & 15;
    const int quad = lane >> 4;
    const float scale = 0.17677669529663687f;

    __shared__ __align__(16) bf16 WqT[32][128];
    __shared__ __align__(16) bf16 pbuf[4][2][16][32];

    for (int p = tid; p < 4096; p += 256) {
        int c = p >> 5, d = p & 31;
        WqT[d][c] = __float2bfloat16(qkv_w[c * 384 + h * 32 + d]);
    }
    __syncthreads();

    const int q0 = tile * 64 + w * 16;
    const bf16* fbase = f2 + ((size_t)(b * NN + q0 + lq)) * 128;
    f32x4 qc0 = {0.f, 0.f, 0.f, 0.f}, qc1 = {0.f, 0.f, 0.f, 0.f};
    #pragma unroll
    for (int kc = 0; kc < 4; ++kc) {
        short8 af = *(const short8*)(fbase + kc * 32 + quad * 8);
        short8 b0 = *(const short8*)(&WqT[lq][kc * 32 + quad * 8]);
        short8 b1 = *(const short8*)(&WqT[16 + lq][kc * 32 + quad * 8]);
        qc0 = __builtin_amdgcn_mfma_f32_16x16x32_bf16(af, b0, qc0, 0, 0, 0);
        qc1 = __builtin_amdgcn_mfma_f32_16x16x32_bf16(af, b1, qc1, 0, 0, 0);
    }
    {
        bf16* pw = &pbuf[w][0][0][0];
        #pragma unroll
        for (int r = 0; r < 4; ++r) {
            int qq = quad * 4 + r;
            pw[qq * 32 + lq]      = __float2bfloat16(qc0[r] * scale);
            pw[qq * 32 + 16 + lq] = __float2bfloat16(qc1[r] * scale);
        }
    }
    __syncthreads();
    const short8 qfrag = *(const short8*)(&pbuf[w][0][lq][quad * 8]);
    __syncthreads();

    const bf16* kb = kk + (size_t)(b * 4 + h) * 2048 * 32;
    const bf16* vb = vt + (size_t)(b * 4 + h) * 32 * 2048;
    f32x4 o0 = {0.f, 0.f, 0.f, 0.f}, o1 = {0.f, 0.f, 0.f, 0.f};
    f32x4 lsum = {0.f, 0.f, 0.f, 0.f};
    const short8 ones = {(short)0x3F80, (short)0x3F80, (short)0x3F80, (short)0x3F80,
                         (short)0x3F80, (short)0x3F80, (short)0x3F80, (short)0x3F80};

    for (int ch = 0; ch < 64; ++ch) {
        const int j0 = ch * 32;
        short8 kf0 = *(const short8*)(kb + (size_t)(j0 + lq) * 32 + quad * 8);
        short8 kf1 = *(const short8*)(kb + (size_t)(j0 + 16 + lq) * 32 + quad * 8);
        f32x4 z = {0.f, 0.f, 0.f, 0.f};
        f32x4 s0 = __builtin_amdgcn_mfma_f32_16x16x32_bf16(qfrag, kf0, z, 0, 0, 0);
        f32x4 s1 = __builtin_amdgcn_mfma_f32_16x16x32_bf16(qfrag, kf1, z, 0, 0, 0);
        bf16* pw = &pbuf[w][ch & 1][0][0];
        #pragma unroll
        for (int r = 0; r < 4; ++r) {
            int qq = quad * 4 + r;
            pw[qq * 32 + lq]      = __float2bfloat16(__expf(s0[r]));
            pw[qq * 32 + 16 + lq] = __float2bfloat16(__expf(s1[r]));
        }
        __syncthreads();
        short8 pf = *(const short8*)(pw + lq * 32 + quad * 8);
        short8 vf0 = *(const short8*)(vb + (size_t)lq * 2048 + j0 + quad * 8);
        short8 vf1 = *(const short8*)(vb + (size_t)(16 + lq) * 2048 + j0 + quad * 8);
        o0   = __builtin_amdgcn_mfma_f32_16x16x32_bf16(pf, vf0, o0, 0, 0, 0);
        o1   = __builtin_amdgcn_mfma_f32_16x16x32_bf16(pf, vf1, o1, 0, 0, 0);
        lsum = __builtin_amdgcn_mfma_f32_16x16x32_bf16(pf, ones, lsum, 0, 0, 0);
    }

    #pragma unroll
    for (int r = 0; r < 4; ++r) {
        int row = q0 + quad * 4 + r;
        float inv = 1.f / lsum[r];
        bf16* orow = atth + ((size_t)(b * NN + row)) * 128 + h * 32;
        orow[lq]      = __float2bfloat16(o0[r] * inv);
        orow[16 + lq] = __float2bfloat16(o1[r] * inv);
    }
}

// ---------------------------------------------------------------- fused out-proj + concat + refine MLP + log_softmax
__global__ __launch_bounds__(128) void final_kernel(
        const bf16* __restrict__ f2, const float* __restrict__ glob,
        const bf16* __restrict__ atth,
        const float* __restrict__ out_w, const float* __restrict__ out_b,
        const float* __restrict__ r1_w, const float* __restrict__ r1_b,
        const float* __restrict__ r2_w, const float* __restrict__ r2_b,
        const float* __restrict__ r3_w, const float* __restrict__ r3_b,
        float* __restrict__ out) {
    const int bn0 = blockIdx.x * 4;
    const int b = bn0 >> 11;
    const int tid = threadIdx.x;
    __shared__ float attin[4][128], comb[4][384], h1[4][128], h2[4][64];
    __shared__ float logits[4][20], lse[4];

    #pragma unroll
    for (int rr = 0; rr < 4; ++rr) {
        attin[rr][tid]      = b2f(atth[(size_t)(bn0 + rr) * 128 + tid]);
        comb[rr][tid]       = b2f(f2[(size_t)(bn0 + rr) * 128 + tid]);
        comb[rr][128 + tid] = glob[b * 128 + tid];
    }
    __syncthreads();
    {
        float a0 = 0.f, a1 = 0.f, a2 = 0.f, a3 = 0.f;
        for (int c = 0; c < 128; ++c) {
            float wv = out_w[c * 128 + tid];
            a0 += attin[0][c] * wv; a1 += attin[1][c] * wv;
            a2 += attin[2][c] * wv; a3 += attin[3][c] * wv;
        }
        float bb = out_b[tid];
        comb[0][256 + tid] = a0 + bb; comb[1][256 + tid] = a1 + bb;
        comb[2][256 + tid] = a2 + bb; comb[3][256 + tid] = a3 + bb;
    }
    __syncthreads();
    {
        float a0 = 0.f, a1 = 0.f, a2 = 0.f, a3 = 0.f;
        for (int c = 0; c < 384; ++c) {
            float wv = r1_w[c * 128 + tid];
            a0 += comb[0][c] * wv; a1 += comb[1][c] * wv;
            a2 += comb[2][c] * wv; a3 += comb[3][c] * wv;
        }
        float bb = r1_b[tid];
        h1[0][tid] = fmaxf(a0 + bb, 0.f); h1[1][tid] = fmaxf(a1 + bb, 0.f);
        h1[2][tid] = fmaxf(a2 + bb, 0.f); h1[3][tid] = fmaxf(a3 + bb, 0.f);
    }
    __syncthreads();
    if (tid < 64) {
        float a0 = 0.f, a1 = 0.f, a2 = 0.f, a3 = 0.f;
        for (int c = 0; c < 128; ++c) {
            float wv = r2_w[c * 64 + tid];
            a0 += h1[0][c] * wv; a1 += h1[1][c] * wv;
            a2 += h1[2][c] * wv; a3 += h1[3][c] * wv;
        }
        float bb = r2_b[tid];
        h2[0][tid] = fmaxf(a0 + bb, 0.f); h2[1][tid] = fmaxf(a1 + bb, 0.f);
        h2[2][tid] = fmaxf(a2 + bb, 0.f); h2[3][tid] = fmaxf(a3 + bb, 0.f);
    }
    __syncthreads();
    if (tid < 20) {
        float a0 = 0.f, a1 = 0.f, a2 = 0.f, a3 = 0.f;
        for (int c = 0; c < 64; ++c) {
            float wv = r3_w[c * 20 + tid];
            a0 += h2[0][c] * wv; a1 += h2[1][c] * wv;
            a2 += h2[2][c] * wv; a3 += h2[3][c] * wv;
        }
        float bb = r3_b[tid];
        logits[0][tid] = a0 + bb; logits[1][tid] = a1 + bb;
        logits[2][tid] = a2 + bb; logits[3][tid] = a3 + bb;
    }
    __syncthreads();
    if (tid < 4) {
        float m = -INFINITY;
        for (int u = 0; u < 20; ++u) m = fmaxf(m, logits[tid][u]);
        float s = 0.f;
        for (int u = 0; u < 20; ++u) s += expf(logits[tid][u] - m);
        lse[tid] = m + logf(s);
    }
    __syncthreads();
    if (tid < 80) {
        int rr = tid / 20, cls = tid % 20;
        out[(size_t)(bn0 + rr) * 20 + cls] = logits[rr][cls] - lse[rr];
    }
}

// ----------------------------------------------------------------------------
// Layout (ws >= NEED_A = 16,846,848 B — proven: Path A ran in round 10):
//   [0,4M)       f1T (phases 1-3) -> f2 bf16 (phase 3+)
//   [4M,+64K)    sqb | [4M+64K,8M+64K) f1 | [8M+64K,+640K) knn | +192K xT3
//   [4M,8M)      kkA (after ec2; f1/sqb dead) | [8M,12M) vtA
//   [12M,16M)    G (gemmG scratch, phases 1-3) -> atth (attention phase)
//   [16M,+68K)   pmax | glob
extern "C" void kernel_launch(void* const* d_in, const int* in_sizes, int n_in,
                              void* d_out, int out_size, void* d_ws, size_t ws_size,
                              hipStream_t stream) {
    const float* x      = (const float*)d_in[0];
    const float* ec1_w1 = (const float*)d_in[2];
    const float* ec1_b1 = (const float*)d_in[3];
    const float* ec1_w2 = (const float*)d_in[4];
    const float* ec1_b2 = (const float*)d_in[5];
    const float* ec2_w1 = (const float*)d_in[6];
    const float* ec2_b1 = (const float*)d_in[7];
    const float* ec2_w2 = (const float*)d_in[8];
    const float* ec2_b2 = (const float*)d_in[9];
    const float* qkv_w  = (const float*)d_in[10];
    const float* out_w  = (const float*)d_in[11];
    const float* out_b  = (const float*)d_in[12];
    const float* r1_w   = (const float*)d_in[13];
    const float* r1_b   = (const float*)d_in[14];
    const float* r2_w   = (const float*)d_in[15];
    const float* r2_b   = (const float*)d_in[16];
    const float* r3_w   = (const float*)d_in[17];
    const float* r3_b   = (const float*)d_in[18];
    float* out = (float*)d_out;

    const size_t MB = 1024 * 1024;
    const size_t NEED_A = 16 * MB + 65536 + 4096;
    if (ws_size < NEED_A) return;   // guard (clean numeric fail, not a fault)

    char* base = (char*)d_ws;
    bf16*  f2   = (bf16*)(base);
    float* f1T  = (float*)(base);
    float* sqb  = (float*)(base + 4 * MB);
    float* f1   = (float*)(base + 4 * MB + 65536);
    u16*   knn  = (u16*)(base + 8 * MB + 65536);
    float* xT3  = (float*)(base + 8 * MB + 65536 + 655360);
    float* G    = (float*)(base + 12 * MB);           // phases 1-3
    bf16*  kkA  = (bf16*)(base + 4 * MB);             // attention phase
    bf16*  vtA  = (bf16*)(base + 8 * MB);
    bf16*  atth = (bf16*)(base + 12 * MB);
    float* pmax = (float*)(base + 16 * MB);
    float* glob = (float*)(base + 16 * MB + 65536);

    sqT_kernel<3><<<BBNN / 256, 256, 0, stream>>>(x, sqb, xT3);
    knn1_kernel<3><<<BB * 256, 512, 0, stream>>>(x, xT3, sqb, knn);
    gemmG_kernel<3><<<BBNN / 4, 256, 0, stream>>>(x, ec1_w1, G);
    edgeconv3_kernel<3, 64, false><<<BBNN / 4, 256, 0, stream>>>(
        x, knn, ec1_w1, ec1_b1, ec1_w2, ec1_b2, G, f1);

    sqT_kernel<64><<<BBNN / 256, 256, 0, stream>>>(f1, sqb, f1T);
    knn_fast_kernel<64, 8><<<BB * 128, 512, 0, stream>>>(f1, f1T, sqb, knn);
    gemmG_kernel<64><<<BBNN / 4, 256, 0, stream>>>(f1, ec2_w1, G);
    edgeconv3_kernel<64, 128, true><<<BBNN / 4, 256, 0, stream>>>(
        f1, knn, ec2_w1, ec2_b1, ec2_w2, ec2_b2, G, f2);

    gmax1_kernel<<<BB * 16, 128, 0, stream>>>(f2, pmax);
    gmax2_kernel<<<BB, 128, 0, stream>>>(pmax, glob);

    kvt_kernel<<<4 * BBNN / 4, 256, 0, stream>>>(f2, qkv_w, kkA, vtA);
    attn_mfma_kernel<<<BB * 4 * 32, 256, 0, stream>>>(f2, qkv_w, kkA, vtA, atth);

    final_kernel<<<BBNN / 4, 128, 0, stream>>>(
        f2, glob, atth, out_w, out_b, r1_w, r1_b, r2_w, r2_b, r3_w, r3_b, out);
}

// Round 13
// 751.880 us; speedup vs baseline: 1.0327x; 1.0327x over previous
//
#include <hip/hip_runtime.h>
#include <hip/hip_bf16.h>

#define BB 8
#define NN 2048
#define KK 20
#define BBNN (BB * NN)

typedef __hip_bfloat16 bf16;
typedef unsigned short u16;
typedef __attribute__((ext_vector_type(8))) short short8;
typedef __attribute__((ext_vector_type(4))) float f32x4;

__device__ __forceinline__ float b2f(bf16 v) { return __bfloat162float(v); }

// ---------------------------------------------------------------- sq + transpose (fused)
template<int C>
__global__ __launch_bounds__(256) void sqT_kernel(const float* __restrict__ xin,
                                                  float* __restrict__ sq,
                                                  float* __restrict__ xT) {
    int t = blockIdx.x * 256 + threadIdx.x;
    if (t >= BBNN) return;
    const float* p = xin + (size_t)t * C;
    float s = 0.f;
    for (int c = 0; c < C; ++c) {
        float v = p[c];
        s += v * v;
        xT[(size_t)c * BBNN + t] = v;
    }
    sq[t] = s;
}

// ---------------------------------------------------------------- kNN, 1 query/wave (for C=3)
// Proven round 11: single-query live set (~50 regs) compiles spill-free.
template<int C>
__global__ __launch_bounds__(512, 4) void knn1_kernel(
        const float* __restrict__ xrows,
        const float* __restrict__ xT,
        const float* __restrict__ sq,
        u16* __restrict__ idx_out) {
    __shared__ __align__(16) float xs[C][2048];
    const int blk = blockIdx.x;            // BB * 256
    const int b = blk >> 8;
    const int tile = blk & 255;
    const int w = threadIdx.x >> 6;
    const int s = threadIdx.x & 63;
    const int tid = threadIdx.x;
    const int iA = tile * 8 + w;
    const int bn0 = b * NN;

    float dA[32];
    #pragma unroll
    for (int r = 0; r < 32; ++r) dA[r] = 0.f;

    for (int u = tid; u < C * 512; u += 512) {
        int row = u / 512, c4 = u % 512;
        *(float4*)&xs[row][c4 * 4] =
            *(const float4*)(xT + (size_t)row * BBNN + bn0 + c4 * 4);
    }
    __syncthreads();

    const int qbase = __builtin_amdgcn_readfirstlane((bn0 + iA) * C);
    float xq[C];
    #pragma unroll
    for (int cc = 0; cc < C; ++cc) xq[cc] = xrows[qbase + cc];

    #pragma unroll
    for (int t = 0; t < 8; ++t) {
        float a0 = 0.f, a1 = 0.f, a2 = 0.f, a3 = 0.f;
        #pragma unroll
        for (int cc = 0; cc < C; ++cc) {
            float4 xv = *(const float4*)&xs[cc][t * 256 + s * 4];
            float q = xq[cc];
            a0 += q * xv.x; a1 += q * xv.y; a2 += q * xv.z; a3 += q * xv.w;
        }
        dA[t * 4 + 0] += a0; dA[t * 4 + 1] += a1;
        dA[t * 4 + 2] += a2; dA[t * 4 + 3] += a3;
    }
    const float sqi = sq[bn0 + iA];
    #pragma unroll
    for (int r = 0; r < 32; ++r) {
        int j = ((r >> 2) << 8) + (s << 2) + (r & 3);
        dA[r] = (sqi + sq[bn0 + j]) - 2.f * dA[r];
    }

    unsigned rm = 0u;
    float m1 = INFINITY, m2 = INFINITY;
    int j1 = 0x7fffffff, j2 = 0x7fffffff;
    #pragma unroll
    for (int r = 0; r < 32; ++r) {
        int j = ((r >> 2) << 8) + (s << 2) + (r & 3);
        float d = dA[r];
        bool l1 = d < m1, l2 = d < m2;
        m2 = l1 ? m1 : (l2 ? d : m2);
        j2 = l1 ? j1 : (l2 ? j : j2);
        m1 = l1 ? d : m1;  j1 = l1 ? j : j1;
    }
    for (int k = 0; k < KK; ++k) {
        if (__any(j1 < 0)) {
            if (j1 < 0) {
                m1 = INFINITY; m2 = INFINITY; j1 = 0x7fffffff; j2 = 0x7fffffff;
                #pragma unroll
                for (int r = 0; r < 32; ++r) {
                    int j = ((r >> 2) << 8) + (s << 2) + (r & 3);
                    float d = (rm & (1u << r)) ? INFINITY : dA[r];
                    bool l1 = d < m1, l2 = d < m2;
                    m2 = l1 ? m1 : (l2 ? d : m2);
                    j2 = l1 ? j1 : (l2 ? j : j2);
                    m1 = l1 ? d : m1;  j1 = l1 ? j : j1;
                }
            }
        }
        float rd = m1; int rj = j1;
        #pragma unroll
        for (int m = 1; m < 64; m <<= 1) {
            float od = __shfl_xor(rd, m); int oj = __shfl_xor(rj, m);
            if (od < rd || (od == rd && oj < rj)) { rd = od; rj = oj; }
        }
        if (s == 0) idx_out[(size_t)(bn0 + iA) * KK + k] = (u16)rj;
        if (k + 1 < KK) {
            if (s == ((rj >> 2) & 63)) {
                int rr = ((rj >> 8) << 2) + (rj & 3);
                rm |= (1u << rr);
                m1 = m2; j1 = j2; m2 = INFINITY; j2 = -1;
            }
        }
    }
}

// ---------------------------------------------------------------- fast kNN v12 (restored; best known for C=64)
// Round 12's sequential selection regressed (196us, 109MB scratch): parking
// dB across A's ballot loop spilled it wholesale. v12's interleaved selection
// (183us, 54MB scratch) is the measured floor for this structure -- restored
// verbatim. Six selection variants land 183-196us: structural floor.
template<int C, int CH>
__global__ __launch_bounds__(512, 4) void knn_fast_kernel(
        const float* __restrict__ xrows,
        const float* __restrict__ xT,
        const float* __restrict__ sq,
        u16* __restrict__ idx_out) {
    __shared__ __align__(16) float xs[CH][2048];
    const int blk = blockIdx.x;            // BB * 128
    const int b = blk >> 7;
    const int tile = blk & 127;
    const int w = threadIdx.x >> 6;
    const int s = threadIdx.x & 63;
    const int iA = tile * 16 + w * 2;
    const int bn0 = b * NN;
    constexpr int NCH = C / CH;            // 8 for <64,8>

    float dA[32], dB[32];
    #pragma unroll
    for (int r = 0; r < 32; ++r) { dA[r] = 0.f; dB[r] = 0.f; }

    const int qbase = __builtin_amdgcn_readfirstlane((bn0 + iA) * C);

    for (int ch = 0; ch < NCH; ++ch) {
        __syncthreads();   // WAR guard vs previous phase's readers
        for (int u = threadIdx.x; u < CH * 512; u += 512) {
            int row = u >> 9, c4 = u & 511;
            *(float4*)&xs[row][c4 * 4] =
                *(const float4*)(xT + (size_t)(ch * CH + row) * BBNN + bn0 + c4 * 4);
        }
        __syncthreads();
        float xqA[CH], xqB[CH];            // wave-uniform -> scalar loads
        #pragma unroll
        for (int cc = 0; cc < CH; ++cc) {
            xqA[cc] = xrows[qbase + ch * CH + cc];
            xqB[cc] = xrows[qbase + C + ch * CH + cc];
        }
        #pragma unroll
        for (int t = 0; t < 8; ++t) {      // unrolled -> dA/dB indices static
            float aA0 = 0.f, aA1 = 0.f, aA2 = 0.f, aA3 = 0.f;
            float aB0 = 0.f, aB1 = 0.f, aB2 = 0.f, aB3 = 0.f;
            #pragma unroll
            for (int cc = 0; cc < CH; ++cc) {
                float4 xv = *(const float4*)&xs[cc][t * 256 + s * 4];
                float qA = xqA[cc], qB = xqB[cc];
                aA0 += qA * xv.x; aA1 += qA * xv.y; aA2 += qA * xv.z; aA3 += qA * xv.w;
                aB0 += qB * xv.x; aB1 += qB * xv.y; aB2 += qB * xv.z; aB3 += qB * xv.w;
            }
            dA[t * 4 + 0] += aA0; dA[t * 4 + 1] += aA1;
            dA[t * 4 + 2] += aA2; dA[t * 4 + 3] += aA3;
            dB[t * 4 + 0] += aB0; dB[t * 4 + 1] += aB1;
            dB[t * 4 + 2] += aB2; dB[t * 4 + 3] += aB3;
        }
    }
    const float sqiA = sq[bn0 + iA];
    const float sqiB = sq[bn0 + iA + 1];
    #pragma unroll
    for (int r = 0; r < 32; ++r) {
        int j = ((r >> 2) << 8) + (s << 2) + (r & 3);
        float sqj = sq[bn0 + j];
        dA[r] = (sqiA + sqj) - 2.f * dA[r];
        dB[r] = (sqiB + sqj) - 2.f * dB[r];
    }

    // ---- selection: interleaved A/B, per-lane top-2 cache, removal bitmask ----
    unsigned rmA = 0u, rmB = 0u;           // removed-candidate bits (per lane)
    float m1A = INFINITY, m2A = INFINITY, m1B = INFINITY, m2B = INFINITY;
    int j1A = 0x7fffffff, j2A = 0x7fffffff, j1B = 0x7fffffff, j2B = 0x7fffffff;
    #pragma unroll
    for (int r = 0; r < 32; ++r) {
        int j = ((r >> 2) << 8) + (s << 2) + (r & 3);
        float d = dA[r];
        bool l1 = d < m1A, l2 = d < m2A;
        m2A = l1 ? m1A : (l2 ? d : m2A);
        j2A = l1 ? j1A : (l2 ? j : j2A);
        m1A = l1 ? d : m1A;  j1A = l1 ? j : j1A;
        d = dB[r];
        l1 = d < m1B; l2 = d < m2B;
        m2B = l1 ? m1B : (l2 ? d : m2B);
        j2B = l1 ? j1B : (l2 ? j : j2B);
        m1B = l1 ? d : m1B;  j1B = l1 ? j : j1B;
    }

    for (int k = 0; k < KK; ++k) {
        // refill lanes whose m1 went invalid (won twice since last scan)
        if (__any(j1A < 0)) {
            if (j1A < 0) {
                m1A = INFINITY; m2A = INFINITY; j1A = 0x7fffffff; j2A = 0x7fffffff;
                #pragma unroll
                for (int r = 0; r < 32; ++r) {
                    int j = ((r >> 2) << 8) + (s << 2) + (r & 3);
                    float d = (rmA & (1u << r)) ? INFINITY : dA[r];
                    bool l1 = d < m1A, l2 = d < m2A;
                    m2A = l1 ? m1A : (l2 ? d : m2A);
                    j2A = l1 ? j1A : (l2 ? j : j2A);
                    m1A = l1 ? d : m1A;  j1A = l1 ? j : j1A;
                }
            }
        }
        if (__any(j1B < 0)) {
            if (j1B < 0) {
                m1B = INFINITY; m2B = INFINITY; j1B = 0x7fffffff; j2B = 0x7fffffff;
                #pragma unroll
                for (int r = 0; r < 32; ++r) {
                    int j = ((r >> 2) << 8) + (s << 2) + (r & 3);
                    float d = (rmB & (1u << r)) ? INFINITY : dB[r];
                    bool l1 = d < m1B, l2 = d < m2B;
                    m2B = l1 ? m1B : (l2 ? d : m2B);
                    j2B = l1 ? j1B : (l2 ? j : j2B);
                    m1B = l1 ? d : m1B;  j1B = l1 ? j : j1B;
                }
            }
        }
        // interleaved 64-lane argmin butterflies (independent chains)
        float rdA = m1A, rdB = m1B; int rjA = j1A, rjB = j1B;
        #pragma unroll
        for (int m = 1; m < 64; m <<= 1) {
            float odA = __shfl_xor(rdA, m); int ojA = __shfl_xor(rjA, m);
            float odB = __shfl_xor(rdB, m); int ojB = __shfl_xor(rjB, m);
            if (odA < rdA || (odA == rdA && ojA < rjA)) { rdA = odA; rjA = ojA; }
            if (odB < rdB || (odB == rdB && ojB < rjB)) { rdB = odB; rjB = ojB; }
        }
        if (s == 0) {
            idx_out[(size_t)(bn0 + iA) * KK + k]     = (u16)rjA;
            idx_out[(size_t)(bn0 + iA + 1) * KK + k] = (u16)rjB;
        }
        if (k + 1 < KK) {
            if (s == ((rjA >> 2) & 63)) {
                int rr = ((rjA >> 8) << 2) + (rjA & 3);
                rmA |= (1u << rr);
                m1A = m2A; j1A = j2A; m2A = INFINITY; j2A = -1;
            }
            if (s == ((rjB >> 2) & 63)) {
                int rr = ((rjB >> 8) << 2) + (rjB & 3);
                rmB |= (1u << rr);
                m1B = m2B; j1B = j2B; m2B = INFINITY; j2B = -1;
            }
        }
    }
}

// ---------------------------------------------------------------- G[n][h] = x[n] . w1_lower[.][h]
// w1 row-major [2*CIN][64]; lower half = rows CIN..2CIN-1 (the (xj-xi) part).
template<int CIN>
__global__ __launch_bounds__(256) void gemmG_kernel(const float* __restrict__ xin,
                                                    const float* __restrict__ w1,
                                                    float* __restrict__ G) {
    __shared__ float wls[CIN * 64];
    __shared__ float xr[4][CIN];
    const int bn0 = blockIdx.x * 4;
    const int tid = threadIdx.x;
    for (int p = tid; p < CIN * 64; p += 256) wls[p] = w1[CIN * 64 + p];
    for (int p = tid; p < 4 * CIN; p += 256)
        xr[p / CIN][p % CIN] = xin[(size_t)bn0 * CIN + p];
    __syncthreads();
    const int pp = tid >> 6, h = tid & 63;
    float a = 0.f;
    for (int c = 0; c < CIN; ++c) a += xr[pp][c] * wls[c * 64 + h];
    G[(size_t)(bn0 + pp) * 64 + h] = a;
}

// ---------------------------------------------------------------- EdgeConv v3: G-decomposed
// 4 points/block. Layer1 per edge = gather G[j] + add (no MACs):
//   h1[k][h] = relu( (b1[h] + xi.W1u[h] - G[i][h]) + G[j][h] )   [algebraically
//   identical to relu(b1 + xi.W1u + (xj-xi).W1l); fp reorder only]
// Layer2: thread owns output column o; W2 column held in 64 VGPRs (loaded once
// from global, L2-resident) -> pure v_fmac_f32 with h1 float4 LDS broadcasts.
template<int CIN, int COUT, bool BF16OUT>
__global__ __launch_bounds__(256) void edgeconv3_kernel(
        const float* __restrict__ xin, const u16* __restrict__ knn,
        const float* __restrict__ w1, const float* __restrict__ b1,
        const float* __restrict__ w2, const float* __restrict__ b2,
        const float* __restrict__ G, void* __restrict__ out) {
    constexpr int SPLIT = 256 / COUT;      // 2 for COUT=128, 4 for COUT=64
    constexpr int KPS = KK / SPLIT;        // 10 / 5
    const int bn0 = blockIdx.x * 4;
    const int b = bn0 >> 11;
    const int tid = threadIdx.x;
    __shared__ float w1us[CIN * 64];                   // upper half (xi part)
    __shared__ float xr[4][CIN];
    __shared__ __align__(16) float h1s[4][KK][64];
    __shared__ float pms[4][SPLIT][COUT];
    __shared__ int js[4][KK];

    for (int p = tid; p < CIN * 64; p += 256) w1us[p] = w1[p];
    for (int p = tid; p < 4 * CIN; p += 256)
        xr[p / CIN][p % CIN] = xin[(size_t)bn0 * CIN + p];
    if (tid < 4 * KK) {
        int j = knn[(size_t)(bn0 + tid / KK) * KK + (tid % KK)];
        js[tid / KK][tid % KK] = (j < NN) ? j : 0;
    }
    __syncthreads();

    // phase 1: h1[pp][k][h]
    {
        const int pp = tid >> 6, h = tid & 63;
        float u = b1[h];
        for (int c = 0; c < CIN; ++c) u += xr[pp][c] * w1us[c * 64 + h];
        u -= G[(size_t)(bn0 + pp) * 64 + h];
        const float* Gb = G + (size_t)b * NN * 64 + h;
        for (int k = 0; k < KK; ++k) {
            float gj = Gb[(size_t)js[pp][k] * 64];
            h1s[pp][k][h] = fmaxf(u + gj, 0.f);
        }
    }
    __syncthreads();

    // phase 2: layer2, W2 column in registers
    {
        const int o = tid % COUT, ks = tid / COUT;
        float wcol[64];
        #pragma unroll
        for (int c = 0; c < 64; ++c) wcol[c] = w2[c * COUT + o];
        #pragma unroll
        for (int pp = 0; pp < 4; ++pp) {
            float mx = -INFINITY;
            for (int k = ks * KPS; k < (ks + 1) * KPS; ++k) {
                float acc = 0.f;
                #pragma unroll
                for (int c4 = 0; c4 < 16; ++c4) {
                    float4 hv = *(const float4*)&h1s[pp][k][c4 * 4];
                    acc += hv.x * wcol[c4 * 4 + 0];
                    acc += hv.y * wcol[c4 * 4 + 1];
                    acc += hv.z * wcol[c4 * 4 + 2];
                    acc += hv.w * wcol[c4 * 4 + 3];
                }
                mx = fmaxf(mx, acc);
            }
            pms[pp][ks][o] = mx;
        }
    }
    __syncthreads();
    for (int idx = tid; idx < 4 * COUT; idx += 256) {
        int pp = idx / COUT, oo = idx % COUT;
        float mx = pms[pp][0][oo];
        #pragma unroll
        for (int s2 = 1; s2 < SPLIT; ++s2) mx = fmaxf(mx, pms[pp][s2][oo]);
        mx += b2[oo];
        if (BF16OUT) ((bf16*)out)[(size_t)(bn0 + pp) * COUT + oo] = __float2bfloat16(mx);
        else         ((float*)out)[(size_t)(bn0 + pp) * COUT + oo] = mx;
    }
}

// ---------------------------------------------------------------- global max over N (2-stage)
__global__ __launch_bounds__(128) void gmax1_kernel(const bf16* __restrict__ f2,
                                                    float* __restrict__ pmax) {
    const int b = blockIdx.x >> 4, ch = blockIdx.x & 15, c = threadIdx.x;
    float m = -INFINITY;
    const bf16* base = f2 + ((size_t)(b * NN + ch * 128)) * 128 + c;
    for (int n = 0; n < 128; ++n) m = fmaxf(m, b2f(base[(size_t)n * 128]));
    pmax[blockIdx.x * 128 + c] = m;
}

__global__ __launch_bounds__(128) void gmax2_kernel(const float* __restrict__ pmax,
                                                    float* __restrict__ glob) {
    const int b = blockIdx.x, c = threadIdx.x;
    float m = -INFINITY;
    for (int ch = 0; ch < 16; ++ch) m = fmaxf(m, pmax[(b * 16 + ch) * 128 + c]);
    glob[b * 128 + c] = m;
}

// ---------------------------------------------------------------- K + V^T for all heads
__global__ __launch_bounds__(256) void kvt_kernel(const bf16* __restrict__ f2,
                                                  const float* __restrict__ qkv_w,
                                                  bf16* __restrict__ kk,
                                                  bf16* __restrict__ vt) {
    const int blk = blockIdx.x;
    const int h = blk >> 12;
    const int rg = blk & 4095;
    const int bn0 = rg * 4;
    const int b = bn0 >> 11, n0 = bn0 & 2047;
    const int tid = threadIdx.x;
    __shared__ float Ws[2][128][32];
    __shared__ float f2s[4][128];
    __shared__ float vbuf[4][32];
    for (int p = tid; p < 2 * 128 * 32; p += 256) {
        int kv = p >> 12, c = (p >> 5) & 127, d = p & 31;
        Ws[kv][c][d] = qkv_w[c * 384 + 128 + kv * 128 + h * 32 + d];
    }
    for (int p = tid; p < 4 * 128; p += 256) {
        int rr = p >> 7, c = p & 127;
        f2s[rr][c] = b2f(f2[(size_t)(bn0 + rr) * 128 + c]);
    }
    __syncthreads();
    const int rr = tid >> 6, u = tid & 63, kv = u >> 5, d = u & 31;
    float acc = 0.f;
    for (int c = 0; c < 128; ++c) acc += f2s[rr][c] * Ws[kv][c][d];
    if (kv == 0)
        kk[((size_t)(b * 4 + h) * 2048 + n0 + rr) * 32 + d] = __float2bfloat16(acc);
    else
        vbuf[rr][d] = acc;
    __syncthreads();
    if (tid < 128) {
        int dd = tid >> 2, r2 = tid & 3;
        vt[((size_t)(b * 4 + h) * 32 + dd) * 2048 + n0 + r2] = __float2bfloat16(vbuf[r2][dd]);
    }
}

// ---------------------------------------------------------------- MFMA flash attention (v2: wave-local pbuf, barriers removed)
// All pbuf accesses are indexed by w -- each wave touches ONLY pbuf[w].
// Same-wave LDS write->read needs no block barrier: DS ops issue in program
// order per wave and the compiler inserts the lgkmcnt wait (same base pointer,
// cannot disprove aliasing). __syncthreads() semantics force a full
// vmcnt(0)+lgkmcnt(0) drain per iteration -- 64 barrier drains that kept the
// K/V global loads from pipelining across chunk iterations, and lockstepped
// 4 independent waves. Only the WqT staging barrier is a real cross-wave dep.
__global__ __launch_bounds__(256) void attn_mfma_kernel(
        const bf16* __restrict__ f2, const float* __restrict__ qkv_w,
        const bf16* __restrict__ kk, const bf16* __restrict__ vt,
        bf16* __restrict__ atth) {
    const int blk = blockIdx.x;
    const int tile = blk & 31;
    const int h = (blk >> 5) & 3;
    const int b = blk >> 7;
    const int tid = threadIdx.x;
    const int w = tid >> 6;
    const int lane = tid & 63;
    const int lq = lane & 15;
    const int quad = lane >> 4;
    const float scale = 0.17677669529663687f;

    __shared__ __align__(16) bf16 WqT[32][128];
    __shared__ __align__(16) bf16 pbuf[4][2][16][32];

    for (int p = tid; p < 4096; p += 256) {
        int c = p >> 5, d = p & 31;
        WqT[d][c] = __float2bfloat16(qkv_w[c * 384 + h * 32 + d]);
    }
    __syncthreads();   // real cross-wave dependency (WqT)

    const int q0 = tile * 64 + w * 16;
    const bf16* fbase = f2 + ((size_t)(b * NN + q0 + lq)) * 128;
    f32x4 qc0 = {0.f, 0.f, 0.f, 0.f}, qc1 = {0.f, 0.f, 0.f, 0.f};
    #pragma unroll
    for (int kc = 0; kc < 4; ++kc) {
        short8 af = *(const short8*)(fbase + kc * 32 + quad * 8);
        short8 b0 = *(const short8*)(&WqT[lq][kc * 32 + quad * 8]);
        short8 b1 = *(const short8*)(&WqT[16 + lq][kc * 32 + quad * 8]);
        qc0 = __builtin_amdgcn_mfma_f32_16x16x32_bf16(af, b0, qc0, 0, 0, 0);
        qc1 = __builtin_amdgcn_mfma_f32_16x16x32_bf16(af, b1, qc1, 0, 0, 0);
    }
    {
        bf16* pw = &pbuf[w][0][0][0];
        #pragma unroll
        for (int r = 0; r < 4; ++r) {
            int qq = quad * 4 + r;
            pw[qq * 32 + lq]      = __float2bfloat16(qc0[r] * scale);
            pw[qq * 32 + 16 + lq] = __float2bfloat16(qc1[r] * scale);
        }
    }
    // same-wave LDS RAW: in-order DS pipeline + compiler lgkmcnt; no barrier
    const short8 qfrag = *(const short8*)(&pbuf[w][0][lq][quad * 8]);

    const bf16* kb = kk + (size_t)(b * 4 + h) * 2048 * 32;
    const bf16* vb = vt + (size_t)(b * 4 + h) * 32 * 2048;
    f32x4 o0 = {0.f, 0.f, 0.f, 0.f}, o1 = {0.f, 0.f, 0.f, 0.f};
    f32x4 lsum = {0.f, 0.f, 0.f, 0.f};
    const short8 ones = {(short)0x3F80, (short)0x3F80, (short)0x3F80, (short)0x3F80,
                         (short)0x3F80, (short)0x3F80, (short)0x3F80, (short)0x3F80};

    for (int ch = 0; ch < 64; ++ch) {
        const int j0 = ch * 32;
        short8 kf0 = *(const short8*)(kb + (size_t)(j0 + lq) * 32 + quad * 8);
        short8 kf1 = *(const short8*)(kb + (size_t)(j0 + 16 + lq) * 32 + quad * 8);
        f32x4 z = {0.f, 0.f, 0.f, 0.f};
        f32x4 s0 = __builtin_amdgcn_mfma_f32_16x16x32_bf16(qfrag, kf0, z, 0, 0, 0);
        f32x4 s1 = __builtin_amdgcn_mfma_f32_16x16x32_bf16(qfrag, kf1, z, 0, 0, 0);
        bf16* pw = &pbuf[w][ch & 1][0][0];
        #pragma unroll
        for (int r = 0; r < 4; ++r) {
            int qq = quad * 4 + r;
            pw[qq * 32 + lq]      = __float2bfloat16(__expf(s0[r]));
            pw[qq * 32 + 16 + lq] = __float2bfloat16(__expf(s1[r]));
        }
        // same-wave LDS RAW (pbuf[w] only); no block barrier -> K/V loads pipeline
        short8 pf = *(const short8*)(pw + lq * 32 + quad * 8);
        short8 vf0 = *(const short8*)(vb + (size_t)lq * 2048 + j0 + quad * 8);
        short8 vf1 = *(const short8*)(vb + (size_t)(16 + lq) * 2048 + j0 + quad * 8);
        o0   = __builtin_amdgcn_mfma_f32_16x16x32_bf16(pf, vf0, o0, 0, 0, 0);
        o1   = __builtin_amdgcn_mfma_f32_16x16x32_bf16(pf, vf1, o1, 0, 0, 0);
        lsum = __builtin_amdgcn_mfma_f32_16x16x32_bf16(pf, ones, lsum, 0, 0, 0);
    }

    #pragma unroll
    for (int r = 0; r < 4; ++r) {
        int row = q0 + quad * 4 + r;
        float inv = 1.f / lsum[r];
        bf16* orow = atth + ((size_t)(b * NN + row)) * 128 + h * 32;
        orow[lq]      = __float2bfloat16(o0[r] * inv);
        orow[16 + lq] = __float2bfloat16(o1[r] * inv);
    }
}

// ---------------------------------------------------------------- fused out-proj + concat + refine MLP + log_softmax
__global__ __launch_bounds__(128) void final_kernel(
        const bf16* __restrict__ f2, const float* __restrict__ glob,
        const bf16* __restrict__ atth,
        const float* __restrict__ out_w, const float* __restrict__ out_b,
        const float* __restrict__ r1_w, const float* __restrict__ r1_b,
        const float* __restrict__ r2_w, const float* __restrict__ r2_b,
        const float* __restrict__ r3_w, const float* __restrict__ r3_b,
        float* __restrict__ out) {
    const int bn0 = blockIdx.x * 4;
    const int b = bn0 >> 11;
    const int tid = threadIdx.x;
    __shared__ float attin[4][128], comb[4][384], h1[4][128], h2[4][64];
    __shared__ float logits[4][20], lse[4];

    #pragma unroll
    for (int rr = 0; rr < 4; ++rr) {
        attin[rr][tid]      = b2f(atth[(size_t)(bn0 + rr) * 128 + tid]);
        comb[rr][tid]       = b2f(f2[(size_t)(bn0 + rr) * 128 + tid]);
        comb[rr][128 + tid] = glob[b * 128 + tid];
    }
    __syncthreads();
    {
        float a0 = 0.f, a1 = 0.f, a2 = 0.f, a3 = 0.f;
        for (int c = 0; c < 128; ++c) {
            float wv = out_w[c * 128 + tid];
            a0 += attin[0][c] * wv; a1 += attin[1][c] * wv;
            a2 += attin[2][c] * wv; a3 += attin[3][c] * wv;
        }
        float bb = out_b[tid];
        comb[0][256 + tid] = a0 + bb; comb[1][256 + tid] = a1 + bb;
        comb[2][256 + tid] = a2 + bb; comb[3][256 + tid] = a3 + bb;
    }
    __syncthreads();
    {
        float a0 = 0.f, a1 = 0.f, a2 = 0.f, a3 = 0.f;
        for (int c = 0; c < 384; ++c) {
            float wv = r1_w[c * 128 + tid];
            a0 += comb[0][c] * wv; a1 += comb[1][c] * wv;
            a2 += comb[2][c] * wv; a3 += comb[3][c] * wv;
        }
        float bb = r1_b[tid];
        h1[0][tid] = fmaxf(a0 + bb, 0.f); h1[1][tid] = fmaxf(a1 + bb, 0.f);
        h1[2][tid] = fmaxf(a2 + bb, 0.f); h1[3][tid] = fmaxf(a3 + bb, 0.f);
    }
    __syncthreads();
    if (tid < 64) {
        float a0 = 0.f, a1 = 0.f, a2 = 0.f, a3 = 0.f;
        for (int c = 0; c < 128; ++c) {
            float wv = r2_w[c * 64 + tid];
            a0 += h1[0][c] * wv; a1 += h1[1][c] * wv;
            a2 += h1[2][c] * wv; a3 += h1[3][c] * wv;
        }
        float bb = r2_b[tid];
        h2[0][tid] = fmaxf(a0 + bb, 0.f); h2[1][tid] = fmaxf(a1 + bb, 0.f);
        h2[2][tid] = fmaxf(a2 + bb, 0.f); h2[3][tid] = fmaxf(a3 + bb, 0.f);
    }
    __syncthreads();
    if (tid < 20) {
        float a0 = 0.f, a1 = 0.f, a2 = 0.f, a3 = 0.f;
        for (int c = 0; c < 64; ++c) {
            float wv = r3_w[c * 20 + tid];
            a0 += h2[0][c] * wv; a1 += h2[1][c] * wv;
            a2 += h2[2][c] * wv; a3 += h2[3][c] * wv;
        }
        float bb = r3_b[tid];
        logits[0][tid] = a0 + bb; logits[1][tid] = a1 + bb;
        logits[2][tid] = a2 + bb; logits[3][tid] = a3 + bb;
    }
    __syncthreads();
    if (tid < 4) {
        float m = -INFINITY;
        for (int u = 0; u < 20; ++u) m = fmaxf(m, logits[tid][u]);
        float s = 0.f;
        for (int u = 0; u < 20; ++u) s += expf(logits[tid][u] - m);
        lse[tid] = m + logf(s);
    }
    __syncthreads();
    if (tid < 80) {
        int rr = tid / 20, cls = tid % 20;
        out[(size_t)(bn0 + rr) * 20 + cls] = logits[rr][cls] - lse[rr];
    }
}

// ----------------------------------------------------------------------------
// Layout (ws >= NEED_A = 16,846,848 B — proven: Path A ran in round 10):
//   [0,4M)       f1T (phases 1-3) -> f2 bf16 (phase 3+)
//   [4M,+64K)    sqb | [4M+64K,8M+64K) f1 | [8M+64K,+640K) knn | +192K xT3
//   [4M,8M)      kkA (after ec2; f1/sqb dead) | [8M,12M) vtA
//   [12M,16M)    G (gemmG scratch, phases 1-3) -> atth (attention phase)
//   [16M,+68K)   pmax | glob
extern "C" void kernel_launch(void* const* d_in, const int* in_sizes, int n_in,
                              void* d_out, int out_size, void* d_ws, size_t ws_size,
                              hipStream_t stream) {
    const float* x      = (const float*)d_in[0];
    const float* ec1_w1 = (const float*)d_in[2];
    const float* ec1_b1 = (const float*)d_in[3];
    const float* ec1_w2 = (const float*)d_in[4];
    const float* ec1_b2 = (const float*)d_in[5];
    const float* ec2_w1 = (const float*)d_in[6];
    const float* ec2_b1 = (const float*)d_in[7];
    const float* ec2_w2 = (const float*)d_in[8];
    const float* ec2_b2 = (const float*)d_in[9];
    const float* qkv_w  = (const float*)d_in[10];
    const float* out_w  = (const float*)d_in[11];
    const float* out_b  = (const float*)d_in[12];
    const float* r1_w   = (const float*)d_in[13];
    const float* r1_b   = (const float*)d_in[14];
    const float* r2_w   = (const float*)d_in[15];
    const float* r2_b   = (const float*)d_in[16];
    const float* r3_w   = (const float*)d_in[17];
    const float* r3_b   = (const float*)d_in[18];
    float* out = (float*)d_out;

    const size_t MB = 1024 * 1024;
    const size_t NEED_A = 16 * MB + 65536 + 4096;
    if (ws_size < NEED_A) return;   // guard (clean numeric fail, not a fault)

    char* base = (char*)d_ws;
    bf16*  f2   = (bf16*)(base);
    float* f1T  = (float*)(base);
    float* sqb  = (float*)(base + 4 * MB);
    float* f1   = (float*)(base + 4 * MB + 65536);
    u16*   knn  = (u16*)(base + 8 * MB + 65536);
    float* xT3  = (float*)(base + 8 * MB + 65536 + 655360);
    float* G    = (float*)(base + 12 * MB);           // phases 1-3
    bf16*  kkA  = (bf16*)(base + 4 * MB);             // attention phase
    bf16*  vtA  = (bf16*)(base + 8 * MB);
    bf16*  atth = (bf16*)(base + 12 * MB);
    float* pmax = (float*)(base + 16 * MB);
    float* glob = (float*)(base + 16 * MB + 65536);

    sqT_kernel<3><<<BBNN / 256, 256, 0, stream>>>(x, sqb, xT3);
    knn1_kernel<3><<<BB * 256, 512, 0, stream>>>(x, xT3, sqb, knn);
    gemmG_kernel<3><<<BBNN / 4, 256, 0, stream>>>(x, ec1_w1, G);
    edgeconv3_kernel<3, 64, false><<<BBNN / 4, 256, 0, stream>>>(
        x, knn, ec1_w1, ec1_b1, ec1_w2, ec1_b2, G, f1);

    sqT_kernel<64><<<BBNN / 256, 256, 0, stream>>>(f1, sqb, f1T);
    knn_fast_kernel<64, 8><<<BB * 128, 512, 0, stream>>>(f1, f1T, sqb, knn);
    gemmG_kernel<64><<<BBNN / 4, 256, 0, stream>>>(f1, ec2_w1, G);
    edgeconv3_kernel<64, 128, true><<<BBNN / 4, 256, 0, stream>>>(
        f1, knn, ec2_w1, ec2_b1, ec2_w2, ec2_b2, G, f2);

    gmax1_kernel<<<BB * 16, 128, 0, stream>>>(f2, pmax);
    gmax2_kernel<<<BB, 128, 0, stream>>>(pmax, glob);

    kvt_kernel<<<4 * BBNN / 4, 256, 0, stream>>>(f2, qkv_w, kkA, vtA);
    attn_mfma_kernel<<<BB * 4 * 32, 256, 0, stream>>>(f2, qkv_w, kkA, vtA, atth);

    final_kernel<<<BBNN / 4, 128, 0, stream>>>(
        f2, glob, atth, out_w, out_b, r1_w, r1_b, r2_w, r2_b, r3_w, r3_b, out);
}

// Round 14
// 726.442 us; speedup vs baseline: 1.0689x; 1.0350x over previous
//
#include <hip/hip_runtime.h>
#include <hip/hip_bf16.h>

#define BB 8
#define NN 2048
#define KK 20
#define BBNN (BB * NN)

typedef __hip_bfloat16 bf16;
typedef unsigned short u16;
typedef __attribute__((ext_vector_type(8))) short short8;
typedef __attribute__((ext_vector_type(4))) float f32x4;

__device__ __forceinline__ float b2f(bf16 v) { return __bfloat162float(v); }

// ---------------------------------------------------------------- sq + transpose (fused)
template<int C>
__global__ __launch_bounds__(256) void sqT_kernel(const float* __restrict__ xin,
                                                  float* __restrict__ sq,
                                                  float* __restrict__ xT) {
    int t = blockIdx.x * 256 + threadIdx.x;
    if (t >= BBNN) return;
    const float* p = xin + (size_t)t * C;
    float s = 0.f;
    for (int c = 0; c < C; ++c) {
        float v = p[c];
        s += v * v;
        xT[(size_t)c * BBNN + t] = v;
    }
    sq[t] = s;
}

// ---------------------------------------------------------------- kNN, 1 query/wave (for C=3)
// Proven round 11: single-query live set (~50 regs) compiles spill-free.
template<int C>
__global__ __launch_bounds__(512, 4) void knn1_kernel(
        const float* __restrict__ xrows,
        const float* __restrict__ xT,
        const float* __restrict__ sq,
        u16* __restrict__ idx_out) {
    __shared__ __align__(16) float xs[C][2048];
    const int blk = blockIdx.x;            // BB * 256
    const int b = blk >> 8;
    const int tile = blk & 255;
    const int w = threadIdx.x >> 6;
    const int s = threadIdx.x & 63;
    const int tid = threadIdx.x;
    const int iA = tile * 8 + w;
    const int bn0 = b * NN;

    float dA[32];
    #pragma unroll
    for (int r = 0; r < 32; ++r) dA[r] = 0.f;

    for (int u = tid; u < C * 512; u += 512) {
        int row = u / 512, c4 = u % 512;
        *(float4*)&xs[row][c4 * 4] =
            *(const float4*)(xT + (size_t)row * BBNN + bn0 + c4 * 4);
    }
    __syncthreads();

    const int qbase = __builtin_amdgcn_readfirstlane((bn0 + iA) * C);
    float xq[C];
    #pragma unroll
    for (int cc = 0; cc < C; ++cc) xq[cc] = xrows[qbase + cc];

    #pragma unroll
    for (int t = 0; t < 8; ++t) {
        float a0 = 0.f, a1 = 0.f, a2 = 0.f, a3 = 0.f;
        #pragma unroll
        for (int cc = 0; cc < C; ++cc) {
            float4 xv = *(const float4*)&xs[cc][t * 256 + s * 4];
            float q = xq[cc];
            a0 += q * xv.x; a1 += q * xv.y; a2 += q * xv.z; a3 += q * xv.w;
        }
        dA[t * 4 + 0] += a0; dA[t * 4 + 1] += a1;
        dA[t * 4 + 2] += a2; dA[t * 4 + 3] += a3;
    }
    const float sqi = sq[bn0 + iA];
    #pragma unroll
    for (int r = 0; r < 32; ++r) {
        int j = ((r >> 2) << 8) + (s << 2) + (r & 3);
        dA[r] = (sqi + sq[bn0 + j]) - 2.f * dA[r];
    }

    unsigned rm = 0u;
    float m1 = INFINITY, m2 = INFINITY;
    int j1 = 0x7fffffff, j2 = 0x7fffffff;
    #pragma unroll
    for (int r = 0; r < 32; ++r) {
        int j = ((r >> 2) << 8) + (s << 2) + (r & 3);
        float d = dA[r];
        bool l1 = d < m1, l2 = d < m2;
        m2 = l1 ? m1 : (l2 ? d : m2);
        j2 = l1 ? j1 : (l2 ? j : j2);
        m1 = l1 ? d : m1;  j1 = l1 ? j : j1;
    }
    for (int k = 0; k < KK; ++k) {
        if (__any(j1 < 0)) {
            if (j1 < 0) {
                m1 = INFINITY; m2 = INFINITY; j1 = 0x7fffffff; j2 = 0x7fffffff;
                #pragma unroll
                for (int r = 0; r < 32; ++r) {
                    int j = ((r >> 2) << 8) + (s << 2) + (r & 3);
                    float d = (rm & (1u << r)) ? INFINITY : dA[r];
                    bool l1 = d < m1, l2 = d < m2;
                    m2 = l1 ? m1 : (l2 ? d : m2);
                    j2 = l1 ? j1 : (l2 ? j : j2);
                    m1 = l1 ? d : m1;  j1 = l1 ? j : j1;
                }
            }
        }
        float rd = m1; int rj = j1;
        #pragma unroll
        for (int m = 1; m < 64; m <<= 1) {
            float od = __shfl_xor(rd, m); int oj = __shfl_xor(rj, m);
            if (od < rd || (od == rd && oj < rj)) { rd = od; rj = oj; }
        }
        if (s == 0) idx_out[(size_t)(bn0 + iA) * KK + k] = (u16)rj;
        if (k + 1 < KK) {
            if (s == ((rj >> 2) & 63)) {
                int rr = ((rj >> 8) << 2) + (rj & 3);
                rm |= (1u << rr);
                m1 = m2; j1 = j2; m2 = INFINITY; j2 = -1;
            }
        }
    }
}

// ---------------------------------------------------------------- fast kNN v12 (restored; best known for C=64)
// Six selection variants land 183-196us: structural floor for this session.
template<int C, int CH>
__global__ __launch_bounds__(512, 4) void knn_fast_kernel(
        const float* __restrict__ xrows,
        const float* __restrict__ xT,
        const float* __restrict__ sq,
        u16* __restrict__ idx_out) {
    __shared__ __align__(16) float xs[CH][2048];
    const int blk = blockIdx.x;            // BB * 128
    const int b = blk >> 7;
    const int tile = blk & 127;
    const int w = threadIdx.x >> 6;
    const int s = threadIdx.x & 63;
    const int iA = tile * 16 + w * 2;
    const int bn0 = b * NN;
    constexpr int NCH = C / CH;            // 8 for <64,8>

    float dA[32], dB[32];
    #pragma unroll
    for (int r = 0; r < 32; ++r) { dA[r] = 0.f; dB[r] = 0.f; }

    const int qbase = __builtin_amdgcn_readfirstlane((bn0 + iA) * C);

    for (int ch = 0; ch < NCH; ++ch) {
        __syncthreads();   // WAR guard vs previous phase's readers
        for (int u = threadIdx.x; u < CH * 512; u += 512) {
            int row = u >> 9, c4 = u & 511;
            *(float4*)&xs[row][c4 * 4] =
                *(const float4*)(xT + (size_t)(ch * CH + row) * BBNN + bn0 + c4 * 4);
        }
        __syncthreads();
        float xqA[CH], xqB[CH];            // wave-uniform -> scalar loads
        #pragma unroll
        for (int cc = 0; cc < CH; ++cc) {
            xqA[cc] = xrows[qbase + ch * CH + cc];
            xqB[cc] = xrows[qbase + C + ch * CH + cc];
        }
        #pragma unroll
        for (int t = 0; t < 8; ++t) {      // unrolled -> dA/dB indices static
            float aA0 = 0.f, aA1 = 0.f, aA2 = 0.f, aA3 = 0.f;
            float aB0 = 0.f, aB1 = 0.f, aB2 = 0.f, aB3 = 0.f;
            #pragma unroll
            for (int cc = 0; cc < CH; ++cc) {
                float4 xv = *(const float4*)&xs[cc][t * 256 + s * 4];
                float qA = xqA[cc], qB = xqB[cc];
                aA0 += qA * xv.x; aA1 += qA * xv.y; aA2 += qA * xv.z; aA3 += qA * xv.w;
                aB0 += qB * xv.x; aB1 += qB * xv.y; aB2 += qB * xv.z; aB3 += qB * xv.w;
            }
            dA[t * 4 + 0] += aA0; dA[t * 4 + 1] += aA1;
            dA[t * 4 + 2] += aA2; dA[t * 4 + 3] += aA3;
            dB[t * 4 + 0] += aB0; dB[t * 4 + 1] += aB1;
            dB[t * 4 + 2] += aB2; dB[t * 4 + 3] += aB3;
        }
    }
    const float sqiA = sq[bn0 + iA];
    const float sqiB = sq[bn0 + iA + 1];
    #pragma unroll
    for (int r = 0; r < 32; ++r) {
        int j = ((r >> 2) << 8) + (s << 2) + (r & 3);
        float sqj = sq[bn0 + j];
        dA[r] = (sqiA + sqj) - 2.f * dA[r];
        dB[r] = (sqiB + sqj) - 2.f * dB[r];
    }

    // ---- selection: interleaved A/B, per-lane top-2 cache, removal bitmask ----
    unsigned rmA = 0u, rmB = 0u;           // removed-candidate bits (per lane)
    float m1A = INFINITY, m2A = INFINITY, m1B = INFINITY, m2B = INFINITY;
    int j1A = 0x7fffffff, j2A = 0x7fffffff, j1B = 0x7fffffff, j2B = 0x7fffffff;
    #pragma unroll
    for (int r = 0; r < 32; ++r) {
        int j = ((r >> 2) << 8) + (s << 2) + (r & 3);
        float d = dA[r];
        bool l1 = d < m1A, l2 = d < m2A;
        m2A = l1 ? m1A : (l2 ? d : m2A);
        j2A = l1 ? j1A : (l2 ? j : j2A);
        m1A = l1 ? d : m1A;  j1A = l1 ? j : j1A;
        d = dB[r];
        l1 = d < m1B; l2 = d < m2B;
        m2B = l1 ? m1B : (l2 ? d : m2B);
        j2B = l1 ? j1B : (l2 ? j : j2B);
        m1B = l1 ? d : m1B;  j1B = l1 ? j : j1B;
    }

    for (int k = 0; k < KK; ++k) {
        // refill lanes whose m1 went invalid (won twice since last scan)
        if (__any(j1A < 0)) {
            if (j1A < 0) {
                m1A = INFINITY; m2A = INFINITY; j1A = 0x7fffffff; j2A = 0x7fffffff;
                #pragma unroll
                for (int r = 0; r < 32; ++r) {
                    int j = ((r >> 2) << 8) + (s << 2) + (r & 3);
                    float d = (rmA & (1u << r)) ? INFINITY : dA[r];
                    bool l1 = d < m1A, l2 = d < m2A;
                    m2A = l1 ? m1A : (l2 ? d : m2A);
                    j2A = l1 ? j1A : (l2 ? j : j2A);
                    m1A = l1 ? d : m1A;  j1A = l1 ? j : j1A;
                }
            }
        }
        if (__any(j1B < 0)) {
            if (j1B < 0) {
                m1B = INFINITY; m2B = INFINITY; j1B = 0x7fffffff; j2B = 0x7fffffff;
                #pragma unroll
                for (int r = 0; r < 32; ++r) {
                    int j = ((r >> 2) << 8) + (s << 2) + (r & 3);
                    float d = (rmB & (1u << r)) ? INFINITY : dB[r];
                    bool l1 = d < m1B, l2 = d < m2B;
                    m2B = l1 ? m1B : (l2 ? d : m2B);
                    j2B = l1 ? j1B : (l2 ? j : j2B);
                    m1B = l1 ? d : m1B;  j1B = l1 ? j : j1B;
                }
            }
        }
        // interleaved 64-lane argmin butterflies (independent chains)
        float rdA = m1A, rdB = m1B; int rjA = j1A, rjB = j1B;
        #pragma unroll
        for (int m = 1; m < 64; m <<= 1) {
            float odA = __shfl_xor(rdA, m); int ojA = __shfl_xor(rjA, m);
            float odB = __shfl_xor(rdB, m); int ojB = __shfl_xor(rjB, m);
            if (odA < rdA || (odA == rdA && ojA < rjA)) { rdA = odA; rjA = ojA; }
            if (odB < rdB || (odB == rdB && ojB < rjB)) { rdB = odB; rjB = ojB; }
        }
        if (s == 0) {
            idx_out[(size_t)(bn0 + iA) * KK + k]     = (u16)rjA;
            idx_out[(size_t)(bn0 + iA + 1) * KK + k] = (u16)rjB;
        }
        if (k + 1 < KK) {
            if (s == ((rjA >> 2) & 63)) {
                int rr = ((rjA >> 8) << 2) + (rjA & 3);
                rmA |= (1u << rr);
                m1A = m2A; j1A = j2A; m2A = INFINITY; j2A = -1;
            }
            if (s == ((rjB >> 2) & 63)) {
                int rr = ((rjB >> 8) << 2) + (rjB & 3);
                rmB |= (1u << rr);
                m1B = m2B; j1B = j2B; m2B = INFINITY; j2B = -1;
            }
        }
    }
}

// ---------------------------------------------------------------- G[n][h] = x[n] . w1_lower[.][h]
// w1 row-major [2*CIN][64]; lower half = rows CIN..2CIN-1 (the (xj-xi) part).
template<int CIN>
__global__ __launch_bounds__(256) void gemmG_kernel(const float* __restrict__ xin,
                                                    const float* __restrict__ w1,
                                                    float* __restrict__ G) {
    __shared__ float wls[CIN * 64];
    __shared__ float xr[4][CIN];
    const int bn0 = blockIdx.x * 4;
    const int tid = threadIdx.x;
    for (int p = tid; p < CIN * 64; p += 256) wls[p] = w1[CIN * 64 + p];
    for (int p = tid; p < 4 * CIN; p += 256)
        xr[p / CIN][p % CIN] = xin[(size_t)bn0 * CIN + p];
    __syncthreads();
    const int pp = tid >> 6, h = tid & 63;
    float a = 0.f;
    for (int c = 0; c < CIN; ++c) a += xr[pp][c] * wls[c * 64 + h];
    G[(size_t)(bn0 + pp) * 64 + h] = a;
}

// ---------------------------------------------------------------- EdgeConv v3: G-decomposed
template<int CIN, int COUT, bool BF16OUT>
__global__ __launch_bounds__(256) void edgeconv3_kernel(
        const float* __restrict__ xin, const u16* __restrict__ knn,
        const float* __restrict__ w1, const float* __restrict__ b1,
        const float* __restrict__ w2, const float* __restrict__ b2,
        const float* __restrict__ G, void* __restrict__ out) {
    constexpr int SPLIT = 256 / COUT;      // 2 for COUT=128, 4 for COUT=64
    constexpr int KPS = KK / SPLIT;        // 10 / 5
    const int bn0 = blockIdx.x * 4;
    const int b = bn0 >> 11;
    const int tid = threadIdx.x;
    __shared__ float w1us[CIN * 64];                   // upper half (xi part)
    __shared__ float xr[4][CIN];
    __shared__ __align__(16) float h1s[4][KK][64];
    __shared__ float pms[4][SPLIT][COUT];
    __shared__ int js[4][KK];

    for (int p = tid; p < CIN * 64; p += 256) w1us[p] = w1[p];
    for (int p = tid; p < 4 * CIN; p += 256)
        xr[p / CIN][p % CIN] = xin[(size_t)bn0 * CIN + p];
    if (tid < 4 * KK) {
        int j = knn[(size_t)(bn0 + tid / KK) * KK + (tid % KK)];
        js[tid / KK][tid % KK] = (j < NN) ? j : 0;
    }
    __syncthreads();

    // phase 1: h1[pp][k][h]
    {
        const int pp = tid >> 6, h = tid & 63;
        float u = b1[h];
        for (int c = 0; c < CIN; ++c) u += xr[pp][c] * w1us[c * 64 + h];
        u -= G[(size_t)(bn0 + pp) * 64 + h];
        const float* Gb = G + (size_t)b * NN * 64 + h;
        for (int k = 0; k < KK; ++k) {
            float gj = Gb[(size_t)js[pp][k] * 64];
            h1s[pp][k][h] = fmaxf(u + gj, 0.f);
        }
    }
    __syncthreads();

    // phase 2: layer2, W2 column in registers
    {
        const int o = tid % COUT, ks = tid / COUT;
        float wcol[64];
        #pragma unroll
        for (int c = 0; c < 64; ++c) wcol[c] = w2[c * COUT + o];
        #pragma unroll
        for (int pp = 0; pp < 4; ++pp) {
            float mx = -INFINITY;
            for (int k = ks * KPS; k < (ks + 1) * KPS; ++k) {
                float acc = 0.f;
                #pragma unroll
                for (int c4 = 0; c4 < 16; ++c4) {
                    float4 hv = *(const float4*)&h1s[pp][k][c4 * 4];
                    acc += hv.x * wcol[c4 * 4 + 0];
                    acc += hv.y * wcol[c4 * 4 + 1];
                    acc += hv.z * wcol[c4 * 4 + 2];
                    acc += hv.w * wcol[c4 * 4 + 3];
                }
                mx = fmaxf(mx, acc);
            }
            pms[pp][ks][o] = mx;
        }
    }
    __syncthreads();
    for (int idx = tid; idx < 4 * COUT; idx += 256) {
        int pp = idx / COUT, oo = idx % COUT;
        float mx = pms[pp][0][oo];
        #pragma unroll
        for (int s2 = 1; s2 < SPLIT; ++s2) mx = fmaxf(mx, pms[pp][s2][oo]);
        mx += b2[oo];
        if (BF16OUT) ((bf16*)out)[(size_t)(bn0 + pp) * COUT + oo] = __float2bfloat16(mx);
        else         ((float*)out)[(size_t)(bn0 + pp) * COUT + oo] = mx;
    }
}

// ---------------------------------------------------------------- global max over N (2-stage)
__global__ __launch_bounds__(128) void gmax1_kernel(const bf16* __restrict__ f2,
                                                    float* __restrict__ pmax) {
    const int b = blockIdx.x >> 4, ch = blockIdx.x & 15, c = threadIdx.x;
    float m = -INFINITY;
    const bf16* base = f2 + ((size_t)(b * NN + ch * 128)) * 128 + c;
    for (int n = 0; n < 128; ++n) m = fmaxf(m, b2f(base[(size_t)n * 128]));
    pmax[blockIdx.x * 128 + c] = m;
}

__global__ __launch_bounds__(128) void gmax2_kernel(const float* __restrict__ pmax,
                                                    float* __restrict__ glob) {
    const int b = blockIdx.x, c = threadIdx.x;
    float m = -INFINITY;
    for (int ch = 0; ch < 16; ++ch) m = fmaxf(m, pmax[(b * 16 + ch) * 128 + c]);
    glob[b * 128 + c] = m;
}

// ---------------------------------------------------------------- K + V^T for all heads (v2)
// Old kvt: 16384 blocks staging 32KB of qkv_w per 4 rows, and the inner loop
// read BOTH operands from LDS (2 ds_read per fma; Ws read is a 64-lane spread)
// -> LDS-issue-bound (~2x256 ds_read/wave/row). v2 uses the proven edgeconv
// phase-2 pattern: thread owns one output column (kv,d), W column in 128 VGPRs
// loaded straight from global (coalesced, L2-resident); activations via float4
// LDS broadcasts (conflict-free). 16 rows/block (grid 4096) amortizes staging
// 4x. Accumulation strictly ascending-c fp32 -> bitwise-identical numerics.
__global__ __launch_bounds__(256) void kvt_kernel(const bf16* __restrict__ f2,
                                                  const float* __restrict__ qkv_w,
                                                  bf16* __restrict__ kk,
                                                  bf16* __restrict__ vt) {
    const int blk = blockIdx.x;            // 4 * (BBNN/16)
    const int h = blk >> 10;
    const int rg = blk & 1023;
    const int bn0 = rg * 16;
    const int b = bn0 >> 11, n0 = bn0 & 2047;
    const int tid = threadIdx.x;
    __shared__ __align__(16) float f2s[16][128];
    __shared__ float vbuf[16][32];

    for (int p = tid; p < 16 * 128; p += 256) {
        int rr = p >> 7, c = p & 127;
        f2s[rr][c] = b2f(f2[(size_t)(bn0 + rr) * 128 + c]);
    }
    const int col = tid & 63, rgrp = tid >> 6;     // col = kv*32+d
    const int kv = col >> 5, d = col & 31;
    float wcol[128];
    #pragma unroll
    for (int c = 0; c < 128; ++c)
        wcol[c] = qkv_w[c * 384 + 128 + kv * 128 + h * 32 + d];
    __syncthreads();

    #pragma unroll
    for (int rq = 0; rq < 4; ++rq) {
        const int rr = rgrp + rq * 4;
        float acc = 0.f;
        #pragma unroll
        for (int c4 = 0; c4 < 32; ++c4) {
            float4 hv = *(const float4*)&f2s[rr][c4 * 4];
            acc += hv.x * wcol[c4 * 4 + 0];
            acc += hv.y * wcol[c4 * 4 + 1];
            acc += hv.z * wcol[c4 * 4 + 2];
            acc += hv.w * wcol[c4 * 4 + 3];
        }
        if (kv == 0)
            kk[((size_t)(b * 4 + h) * 2048 + n0 + rr) * 32 + d] = __float2bfloat16(acc);
        else
            vbuf[rr][d] = acc;
    }
    __syncthreads();
    if (tid < 128) {
        int dd = tid >> 2, r2 = tid & 3;
        #pragma unroll
        for (int rq = 0; rq < 4; ++rq) {
            int r = r2 + rq * 4;
            vt[((size_t)(b * 4 + h) * 32 + dd) * 2048 + n0 + r] = __float2bfloat16(vbuf[r][dd]);
        }
    }
}

// ---------------------------------------------------------------- MFMA flash attention (v2: wave-local pbuf, barriers removed)
__global__ __launch_bounds__(256) void attn_mfma_kernel(
        const bf16* __restrict__ f2, const float* __restrict__ qkv_w,
        const bf16* __restrict__ kk, const bf16* __restrict__ vt,
        bf16* __restrict__ atth) {
    const int blk = blockIdx.x;
    const int tile = blk & 31;
    const int h = (blk >> 5) & 3;
    const int b = blk >> 7;
    const int tid = threadIdx.x;
    const int w = tid >> 6;
    const int lane = tid & 63;
    const int lq = lane & 15;
    const int quad = lane >> 4;
    const float scale = 0.17677669529663687f;

    __shared__ __align__(16) bf16 WqT[32][128];
    __shared__ __align__(16) bf16 pbuf[4][2][16][32];

    for (int p = tid; p < 4096; p += 256) {
        int c = p >> 5, d = p & 31;
        WqT[d][c] = __float2bfloat16(qkv_w[c * 384 + h * 32 + d]);
    }
    __syncthreads();   // real cross-wave dependency (WqT)

    const int q0 = tile * 64 + w * 16;
    const bf16* fbase = f2 + ((size_t)(b * NN + q0 + lq)) * 128;
    f32x4 qc0 = {0.f, 0.f, 0.f, 0.f}, qc1 = {0.f, 0.f, 0.f, 0.f};
    #pragma unroll
    for (int kc = 0; kc < 4; ++kc) {
        short8 af = *(const short8*)(fbase + kc * 32 + quad * 8);
        short8 b0 = *(const short8*)(&WqT[lq][kc * 32 + quad * 8]);
        short8 b1 = *(const short8*)(&WqT[16 + lq][kc * 32 + quad * 8]);
        qc0 = __builtin_amdgcn_mfma_f32_16x16x32_bf16(af, b0, qc0, 0, 0, 0);
        qc1 = __builtin_amdgcn_mfma_f32_16x16x32_bf16(af, b1, qc1, 0, 0, 0);
    }
    {
        bf16* pw = &pbuf[w][0][0][0];
        #pragma unroll
        for (int r = 0; r < 4; ++r) {
            int qq = quad * 4 + r;
            pw[qq * 32 + lq]      = __float2bfloat16(qc0[r] * scale);
            pw[qq * 32 + 16 + lq] = __float2bfloat16(qc1[r] * scale);
        }
    }
    // same-wave LDS RAW: in-order DS pipeline + compiler lgkmcnt; no barrier
    const short8 qfrag = *(const short8*)(&pbuf[w][0][lq][quad * 8]);

    const bf16* kb = kk + (size_t)(b * 4 + h) * 2048 * 32;
    const bf16* vb = vt + (size_t)(b * 4 + h) * 32 * 2048;
    f32x4 o0 = {0.f, 0.f, 0.f, 0.f}, o1 = {0.f, 0.f, 0.f, 0.f};
    f32x4 lsum = {0.f, 0.f, 0.f, 0.f};
    const short8 ones = {(short)0x3F80, (short)0x3F80, (short)0x3F80, (short)0x3F80,
                         (short)0x3F80, (short)0x3F80, (short)0x3F80, (short)0x3F80};

    for (int ch = 0; ch < 64; ++ch) {
        const int j0 = ch * 32;
        short8 kf0 = *(const short8*)(kb + (size_t)(j0 + lq) * 32 + quad * 8);
        short8 kf1 = *(const short8*)(kb + (size_t)(j0 + 16 + lq) * 32 + quad * 8);
        f32x4 z = {0.f, 0.f, 0.f, 0.f};
        f32x4 s0 = __builtin_amdgcn_mfma_f32_16x16x32_bf16(qfrag, kf0, z, 0, 0, 0);
        f32x4 s1 = __builtin_amdgcn_mfma_f32_16x16x32_bf16(qfrag, kf1, z, 0, 0, 0);
        bf16* pw = &pbuf[w][ch & 1][0][0];
        #pragma unroll
        for (int r = 0; r < 4; ++r) {
            int qq = quad * 4 + r;
            pw[qq * 32 + lq]      = __float2bfloat16(__expf(s0[r]));
            pw[qq * 32 + 16 + lq] = __float2bfloat16(__expf(s1[r]));
        }
        // same-wave LDS RAW (pbuf[w] only); no block barrier -> K/V loads pipeline
        short8 pf = *(const short8*)(pw + lq * 32 + quad * 8);
        short8 vf0 = *(const short8*)(vb + (size_t)lq * 2048 + j0 + quad * 8);
        short8 vf1 = *(const short8*)(vb + (size_t)(16 + lq) * 2048 + j0 + quad * 8);
        o0   = __builtin_amdgcn_mfma_f32_16x16x32_bf16(pf, vf0, o0, 0, 0, 0);
        o1   = __builtin_amdgcn_mfma_f32_16x16x32_bf16(pf, vf1, o1, 0, 0, 0);
        lsum = __builtin_amdgcn_mfma_f32_16x16x32_bf16(pf, ones, lsum, 0, 0, 0);
    }

    #pragma unroll
    for (int r = 0; r < 4; ++r) {
        int row = q0 + quad * 4 + r;
        float inv = 1.f / lsum[r];
        bf16* orow = atth + ((size_t)(b * NN + row)) * 128 + h * 32;
        orow[lq]      = __float2bfloat16(o0[r] * inv);
        orow[16 + lq] = __float2bfloat16(o1[r] * inv);
    }
}

// ---------------------------------------------------------------- fused out-proj + concat + refine MLP + log_softmax
__global__ __launch_bounds__(128) void final_kernel(
        const bf16* __restrict__ f2, const float* __restrict__ glob,
        const bf16* __restrict__ atth,
        const float* __restrict__ out_w, const float* __restrict__ out_b,
        const float* __restrict__ r1_w, const float* __restrict__ r1_b,
        const float* __restrict__ r2_w, const float* __restrict__ r2_b,
        const float* __restrict__ r3_w, const float* __restrict__ r3_b,
        float* __restrict__ out) {
    const int bn0 = blockIdx.x * 4;
    const int b = bn0 >> 11;
    const int tid = threadIdx.x;
    __shared__ float attin[4][128], comb[4][384], h1[4][128], h2[4][64];
    __shared__ float logits[4][20], lse[4];

    #pragma unroll
    for (int rr = 0; rr < 4; ++rr) {
        attin[rr][tid]      = b2f(atth[(size_t)(bn0 + rr) * 128 + tid]);
        comb[rr][tid]       = b2f(f2[(size_t)(bn0 + rr) * 128 + tid]);
        comb[rr][128 + tid] = glob[b * 128 + tid];
    }
    __syncthreads();
    {
        float a0 = 0.f, a1 = 0.f, a2 = 0.f, a3 = 0.f;
        for (int c = 0; c < 128; ++c) {
            float wv = out_w[c * 128 + tid];
            a0 += attin[0][c] * wv; a1 += attin[1][c] * wv;
            a2 += attin[2][c] * wv; a3 += attin[3][c] * wv;
        }
        float bb = out_b[tid];
        comb[0][256 + tid] = a0 + bb; comb[1][256 + tid] = a1 + bb;
        comb[2][256 + tid] = a2 + bb; comb[3][256 + tid] = a3 + bb;
    }
    __syncthreads();
    {
        float a0 = 0.f, a1 = 0.f, a2 = 0.f, a3 = 0.f;
        for (int c = 0; c < 384; ++c) {
            float wv = r1_w[c * 128 + tid];
            a0 += comb[0][c] * wv; a1 += comb[1][c] * wv;
            a2 += comb[2][c] * wv; a3 += comb[3][c] * wv;
        }
        float bb = r1_b[tid];
        h1[0][tid] = fmaxf(a0 + bb, 0.f); h1[1][tid] = fmaxf(a1 + bb, 0.f);
        h1[2][tid] = fmaxf(a2 + bb, 0.f); h1[3][tid] = fmaxf(a3 + bb, 0.f);
    }
    __syncthreads();
    if (tid < 64) {
        float a0 = 0.f, a1 = 0.f, a2 = 0.f, a3 = 0.f;
        for (int c = 0; c < 128; ++c) {
            float wv = r2_w[c * 64 + tid];
            a0 += h1[0][c] * wv; a1 += h1[1][c] * wv;
            a2 += h1[2][c] * wv; a3 += h1[3][c] * wv;
        }
        float bb = r2_b[tid];
        h2[0][tid] = fmaxf(a0 + bb, 0.f); h2[1][tid] = fmaxf(a1 + bb, 0.f);
        h2[2][tid] = fmaxf(a2 + bb, 0.f); h2[3][tid] = fmaxf(a3 + bb, 0.f);
    }
    __syncthreads();
    if (tid < 20) {
        float a0 = 0.f, a1 = 0.f, a2 = 0.f, a3 = 0.f;
        for (int c = 0; c < 64; ++c) {
            float wv = r3_w[c * 20 + tid];
            a0 += h2[0][c] * wv; a1 += h2[1][c] * wv;
            a2 += h2[2][c] * wv; a3 += h2[3][c] * wv;
        }
        float bb = r3_b[tid];
        logits[0][tid] = a0 + bb; logits[1][tid] = a1 + bb;
        logits[2][tid] = a2 + bb; logits[3][tid] = a3 + bb;
    }
    __syncthreads();
    if (tid < 4) {
        float m = -INFINITY;
        for (int u = 0; u < 20; ++u) m = fmaxf(m, logits[tid][u]);
        float s = 0.f;
        for (int u = 0; u < 20; ++u) s += expf(logits[tid][u] - m);
        lse[tid] = m + logf(s);
    }
    __syncthreads();
    if (tid < 80) {
        int rr = tid / 20, cls = tid % 20;
        out[(size_t)(bn0 + rr) * 20 + cls] = logits[rr][cls] - lse[rr];
    }
}

// ----------------------------------------------------------------------------
// Layout (ws >= NEED_A = 16,846,848 B — proven: Path A ran in round 10):
//   [0,4M)       f1T (phases 1-3) -> f2 bf16 (phase 3+)
//   [4M,+64K)    sqb | [4M+64K,8M+64K) f1 | [8M+64K,+640K) knn | +192K xT3
//   [4M,8M)      kkA (after ec2; f1/sqb dead) | [8M,12M) vtA
//   [12M,16M)    G (gemmG scratch, phases 1-3) -> atth (attention phase)
//   [16M,+68K)   pmax | glob
extern "C" void kernel_launch(void* const* d_in, const int* in_sizes, int n_in,
                              void* d_out, int out_size, void* d_ws, size_t ws_size,
                              hipStream_t stream) {
    const float* x      = (const float*)d_in[0];
    const float* ec1_w1 = (const float*)d_in[2];
    const float* ec1_b1 = (const float*)d_in[3];
    const float* ec1_w2 = (const float*)d_in[4];
    const float* ec1_b2 = (const float*)d_in[5];
    const float* ec2_w1 = (const float*)d_in[6];
    const float* ec2_b1 = (const float*)d_in[7];
    const float* ec2_w2 = (const float*)d_in[8];
    const float* ec2_b2 = (const float*)d_in[9];
    const float* qkv_w  = (const float*)d_in[10];
    const float* out_w  = (const float*)d_in[11];
    const float* out_b  = (const float*)d_in[12];
    const float* r1_w   = (const float*)d_in[13];
    const float* r1_b   = (const float*)d_in[14];
    const float* r2_w   = (const float*)d_in[15];
    const float* r2_b   = (const float*)d_in[16];
    const float* r3_w   = (const float*)d_in[17];
    const float* r3_b   = (const float*)d_in[18];
    float* out = (float*)d_out;

    const size_t MB = 1024 * 1024;
    const size_t NEED_A = 16 * MB + 65536 + 4096;
    if (ws_size < NEED_A) return;   // guard (clean numeric fail, not a fault)

    char* base = (char*)d_ws;
    bf16*  f2   = (bf16*)(base);
    float* f1T  = (float*)(base);
    float* sqb  = (float*)(base + 4 * MB);
    float* f1   = (float*)(base + 4 * MB + 65536);
    u16*   knn  = (u16*)(base + 8 * MB + 65536);
    float* xT3  = (float*)(base + 8 * MB + 65536 + 655360);
    float* G    = (float*)(base + 12 * MB);           // phases 1-3
    bf16*  kkA  = (bf16*)(base + 4 * MB);             // attention phase
    bf16*  vtA  = (bf16*)(base + 8 * MB);
    bf16*  atth = (bf16*)(base + 12 * MB);
    float* pmax = (float*)(base + 16 * MB);
    float* glob = (float*)(base + 16 * MB + 65536);

    sqT_kernel<3><<<BBNN / 256, 256, 0, stream>>>(x, sqb, xT3);
    knn1_kernel<3><<<BB * 256, 512, 0, stream>>>(x, xT3, sqb, knn);
    gemmG_kernel<3><<<BBNN / 4, 256, 0, stream>>>(x, ec1_w1, G);
    edgeconv3_kernel<3, 64, false><<<BBNN / 4, 256, 0, stream>>>(
        x, knn, ec1_w1, ec1_b1, ec1_w2, ec1_b2, G, f1);

    sqT_kernel<64><<<BBNN / 256, 256, 0, stream>>>(f1, sqb, f1T);
    knn_fast_kernel<64, 8><<<BB * 128, 512, 0, stream>>>(f1, f1T, sqb, knn);
    gemmG_kernel<64><<<BBNN / 4, 256, 0, stream>>>(f1, ec2_w1, G);
    edgeconv3_kernel<64, 128, true><<<BBNN / 4, 256, 0, stream>>>(
        f1, knn, ec2_w1, ec2_b1, ec2_w2, ec2_b2, G, f2);

    gmax1_kernel<<<BB * 16, 128, 0, stream>>>(f2, pmax);
    gmax2_kernel<<<BB, 128, 0, stream>>>(pmax, glob);

    kvt_kernel<<<4 * BBNN / 16, 256, 0, stream>>>(f2, qkv_w, kkA, vtA);
    attn_mfma_kernel<<<BB * 4 * 32, 256, 0, stream>>>(f2, qkv_w, kkA, vtA, atth);

    final_kernel<<<BBNN / 4, 128, 0, stream>>>(
        f2, glob, atth, out_w, out_b, r1_w, r1_b, r2_w, r2_b, r3_w, r3_b, out);
}

// Round 15
// 718.368 us; speedup vs baseline: 1.0809x; 1.0112x over previous
//
#include <hip/hip_runtime.h>
#include <hip/hip_bf16.h>

#define BB 8
#define NN 2048
#define KK 20
#define BBNN (BB * NN)

typedef __hip_bfloat16 bf16;
typedef unsigned short u16;
typedef __attribute__((ext_vector_type(8))) short short8;
typedef __attribute__((ext_vector_type(4))) float f32x4;

__device__ __forceinline__ float b2f(bf16 v) { return __bfloat162float(v); }

// ---------------------------------------------------------------- sq + transpose (fused)
template<int C>
__global__ __launch_bounds__(256) void sqT_kernel(const float* __restrict__ xin,
                                                  float* __restrict__ sq,
                                                  float* __restrict__ xT) {
    int t = blockIdx.x * 256 + threadIdx.x;
    if (t >= BBNN) return;
    const float* p = xin + (size_t)t * C;
    float s = 0.f;
    for (int c = 0; c < C; ++c) {
        float v = p[c];
        s += v * v;
        xT[(size_t)c * BBNN + t] = v;
    }
    sq[t] = s;
}

// ---------------------------------------------------------------- kNN, 1 query/wave (for C=3)
// Proven round 11: single-query live set (~50 regs) compiles spill-free.
template<int C>
__global__ __launch_bounds__(512, 4) void knn1_kernel(
        const float* __restrict__ xrows,
        const float* __restrict__ xT,
        const float* __restrict__ sq,
        u16* __restrict__ idx_out) {
    __shared__ __align__(16) float xs[C][2048];
    const int blk = blockIdx.x;            // BB * 256
    const int b = blk >> 8;
    const int tile = blk & 255;
    const int w = threadIdx.x >> 6;
    const int s = threadIdx.x & 63;
    const int tid = threadIdx.x;
    const int iA = tile * 8 + w;
    const int bn0 = b * NN;

    float dA[32];
    #pragma unroll
    for (int r = 0; r < 32; ++r) dA[r] = 0.f;

    for (int u = tid; u < C * 512; u += 512) {
        int row = u / 512, c4 = u % 512;
        *(float4*)&xs[row][c4 * 4] =
            *(const float4*)(xT + (size_t)row * BBNN + bn0 + c4 * 4);
    }
    __syncthreads();

    const int qbase = __builtin_amdgcn_readfirstlane((bn0 + iA) * C);
    float xq[C];
    #pragma unroll
    for (int cc = 0; cc < C; ++cc) xq[cc] = xrows[qbase + cc];

    #pragma unroll
    for (int t = 0; t < 8; ++t) {
        float a0 = 0.f, a1 = 0.f, a2 = 0.f, a3 = 0.f;
        #pragma unroll
        for (int cc = 0; cc < C; ++cc) {
            float4 xv = *(const float4*)&xs[cc][t * 256 + s * 4];
            float q = xq[cc];
            a0 += q * xv.x; a1 += q * xv.y; a2 += q * xv.z; a3 += q * xv.w;
        }
        dA[t * 4 + 0] += a0; dA[t * 4 + 1] += a1;
        dA[t * 4 + 2] += a2; dA[t * 4 + 3] += a3;
    }
    const float sqi = sq[bn0 + iA];
    #pragma unroll
    for (int r = 0; r < 32; ++r) {
        int j = ((r >> 2) << 8) + (s << 2) + (r & 3);
        dA[r] = (sqi + sq[bn0 + j]) - 2.f * dA[r];
    }

    unsigned rm = 0u;
    float m1 = INFINITY, m2 = INFINITY;
    int j1 = 0x7fffffff, j2 = 0x7fffffff;
    #pragma unroll
    for (int r = 0; r < 32; ++r) {
        int j = ((r >> 2) << 8) + (s << 2) + (r & 3);
        float d = dA[r];
        bool l1 = d < m1, l2 = d < m2;
        m2 = l1 ? m1 : (l2 ? d : m2);
        j2 = l1 ? j1 : (l2 ? j : j2);
        m1 = l1 ? d : m1;  j1 = l1 ? j : j1;
    }
    for (int k = 0; k < KK; ++k) {
        if (__any(j1 < 0)) {
            if (j1 < 0) {
                m1 = INFINITY; m2 = INFINITY; j1 = 0x7fffffff; j2 = 0x7fffffff;
                #pragma unroll
                for (int r = 0; r < 32; ++r) {
                    int j = ((r >> 2) << 8) + (s << 2) + (r & 3);
                    float d = (rm & (1u << r)) ? INFINITY : dA[r];
                    bool l1 = d < m1, l2 = d < m2;
                    m2 = l1 ? m1 : (l2 ? d : m2);
                    j2 = l1 ? j1 : (l2 ? j : j2);
                    m1 = l1 ? d : m1;  j1 = l1 ? j : j1;
                }
            }
        }
        float rd = m1; int rj = j1;
        #pragma unroll
        for (int m = 1; m < 64; m <<= 1) {
            float od = __shfl_xor(rd, m); int oj = __shfl_xor(rj, m);
            if (od < rd || (od == rd && oj < rj)) { rd = od; rj = oj; }
        }
        if (s == 0) idx_out[(size_t)(bn0 + iA) * KK + k] = (u16)rj;
        if (k + 1 < KK) {
            if (s == ((rj >> 2) & 63)) {
                int rr = ((rj >> 8) << 2) + (rj & 3);
                rm |= (1u << rr);
                m1 = m2; j1 = j2; m2 = INFINITY; j2 = -1;
            }
        }
    }
}

// ---------------------------------------------------------------- fast kNN v12 (restored; best known for C=64)
// Six selection variants land 183-196us: structural floor for this session.
template<int C, int CH>
__global__ __launch_bounds__(512, 4) void knn_fast_kernel(
        const float* __restrict__ xrows,
        const float* __restrict__ xT,
        const float* __restrict__ sq,
        u16* __restrict__ idx_out) {
    __shared__ __align__(16) float xs[CH][2048];
    const int blk = blockIdx.x;            // BB * 128
    const int b = blk >> 7;
    const int tile = blk & 127;
    const int w = threadIdx.x >> 6;
    const int s = threadIdx.x & 63;
    const int iA = tile * 16 + w * 2;
    const int bn0 = b * NN;
    constexpr int NCH = C / CH;            // 8 for <64,8>

    float dA[32], dB[32];
    #pragma unroll
    for (int r = 0; r < 32; ++r) { dA[r] = 0.f; dB[r] = 0.f; }

    const int qbase = __builtin_amdgcn_readfirstlane((bn0 + iA) * C);

    for (int ch = 0; ch < NCH; ++ch) {
        __syncthreads();   // WAR guard vs previous phase's readers
        for (int u = threadIdx.x; u < CH * 512; u += 512) {
            int row = u >> 9, c4 = u & 511;
            *(float4*)&xs[row][c4 * 4] =
                *(const float4*)(xT + (size_t)(ch * CH + row) * BBNN + bn0 + c4 * 4);
        }
        __syncthreads();
        float xqA[CH], xqB[CH];            // wave-uniform -> scalar loads
        #pragma unroll
        for (int cc = 0; cc < CH; ++cc) {
            xqA[cc] = xrows[qbase + ch * CH + cc];
            xqB[cc] = xrows[qbase + C + ch * CH + cc];
        }
        #pragma unroll
        for (int t = 0; t < 8; ++t) {      // unrolled -> dA/dB indices static
            float aA0 = 0.f, aA1 = 0.f, aA2 = 0.f, aA3 = 0.f;
            float aB0 = 0.f, aB1 = 0.f, aB2 = 0.f, aB3 = 0.f;
            #pragma unroll
            for (int cc = 0; cc < CH; ++cc) {
                float4 xv = *(const float4*)&xs[cc][t * 256 + s * 4];
                float qA = xqA[cc], qB = xqB[cc];
                aA0 += qA * xv.x; aA1 += qA * xv.y; aA2 += qA * xv.z; aA3 += qA * xv.w;
                aB0 += qB * xv.x; aB1 += qB * xv.y; aB2 += qB * xv.z; aB3 += qB * xv.w;
            }
            dA[t * 4 + 0] += aA0; dA[t * 4 + 1] += aA1;
            dA[t * 4 + 2] += aA2; dA[t * 4 + 3] += aA3;
            dB[t * 4 + 0] += aB0; dB[t * 4 + 1] += aB1;
            dB[t * 4 + 2] += aB2; dB[t * 4 + 3] += aB3;
        }
    }
    const float sqiA = sq[bn0 + iA];
    const float sqiB = sq[bn0 + iA + 1];
    #pragma unroll
    for (int r = 0; r < 32; ++r) {
        int j = ((r >> 2) << 8) + (s << 2) + (r & 3);
        float sqj = sq[bn0 + j];
        dA[r] = (sqiA + sqj) - 2.f * dA[r];
        dB[r] = (sqiB + sqj) - 2.f * dB[r];
    }

    // ---- selection: interleaved A/B, per-lane top-2 cache, removal bitmask ----
    unsigned rmA = 0u, rmB = 0u;           // removed-candidate bits (per lane)
    float m1A = INFINITY, m2A = INFINITY, m1B = INFINITY, m2B = INFINITY;
    int j1A = 0x7fffffff, j2A = 0x7fffffff, j1B = 0x7fffffff, j2B = 0x7fffffff;
    #pragma unroll
    for (int r = 0; r < 32; ++r) {
        int j = ((r >> 2) << 8) + (s << 2) + (r & 3);
        float d = dA[r];
        bool l1 = d < m1A, l2 = d < m2A;
        m2A = l1 ? m1A : (l2 ? d : m2A);
        j2A = l1 ? j1A : (l2 ? j : j2A);
        m1A = l1 ? d : m1A;  j1A = l1 ? j : j1A;
        d = dB[r];
        l1 = d < m1B; l2 = d < m2B;
        m2B = l1 ? m1B : (l2 ? d : m2B);
        j2B = l1 ? j1B : (l2 ? j : j2B);
        m1B = l1 ? d : m1B;  j1B = l1 ? j : j1B;
    }

    for (int k = 0; k < KK; ++k) {
        // refill lanes whose m1 went invalid (won twice since last scan)
        if (__any(j1A < 0)) {
            if (j1A < 0) {
                m1A = INFINITY; m2A = INFINITY; j1A = 0x7fffffff; j2A = 0x7fffffff;
                #pragma unroll
                for (int r = 0; r < 32; ++r) {
                    int j = ((r >> 2) << 8) + (s << 2) + (r & 3);
                    float d = (rmA & (1u << r)) ? INFINITY : dA[r];
                    bool l1 = d < m1A, l2 = d < m2A;
                    m2A = l1 ? m1A : (l2 ? d : m2A);
                    j2A = l1 ? j1A : (l2 ? j : j2A);
                    m1A = l1 ? d : m1A;  j1A = l1 ? j : j1A;
                }
            }
        }
        if (__any(j1B < 0)) {
            if (j1B < 0) {
                m1B = INFINITY; m2B = INFINITY; j1B = 0x7fffffff; j2B = 0x7fffffff;
                #pragma unroll
                for (int r = 0; r < 32; ++r) {
                    int j = ((r >> 2) << 8) + (s << 2) + (r & 3);
                    float d = (rmB & (1u << r)) ? INFINITY : dB[r];
                    bool l1 = d < m1B, l2 = d < m2B;
                    m2B = l1 ? m1B : (l2 ? d : m2B);
                    j2B = l1 ? j1B : (l2 ? j : j2B);
                    m1B = l1 ? d : m1B;  j1B = l1 ? j : j1B;
                }
            }
        }
        // interleaved 64-lane argmin butterflies (independent chains)
        float rdA = m1A, rdB = m1B; int rjA = j1A, rjB = j1B;
        #pragma unroll
        for (int m = 1; m < 64; m <<= 1) {
            float odA = __shfl_xor(rdA, m); int ojA = __shfl_xor(rjA, m);
            float odB = __shfl_xor(rdB, m); int ojB = __shfl_xor(rjB, m);
            if (odA < rdA || (odA == rdA && ojA < rjA)) { rdA = odA; rjA = ojA; }
            if (odB < rdB || (odB == rdB && ojB < rjB)) { rdB = odB; rjB = ojB; }
        }
        if (s == 0) {
            idx_out[(size_t)(bn0 + iA) * KK + k]     = (u16)rjA;
            idx_out[(size_t)(bn0 + iA + 1) * KK + k] = (u16)rjB;
        }
        if (k + 1 < KK) {
            if (s == ((rjA >> 2) & 63)) {
                int rr = ((rjA >> 8) << 2) + (rjA & 3);
                rmA |= (1u << rr);
                m1A = m2A; j1A = j2A; m2A = INFINITY; j2A = -1;
            }
            if (s == ((rjB >> 2) & 63)) {
                int rr = ((rjB >> 8) << 2) + (rjB & 3);
                rmB |= (1u << rr);
                m1B = m2B; j1B = j2B; m2B = INFINITY; j2B = -1;
            }
        }
    }
}

// ---------------------------------------------------------------- G[n][h] = x[n] . w1_lower[.][h]  (v2)
// Old: 4 rows/block, 16KB weight staging, 2 LDS reads per fma (spread + bcast).
// v2 (kvt-v2 pattern): 16 rows/block (grid BBNN/16), thread owns column h with
// wcol[CIN] in VGPRs from global (coalesced, L2-resident); activations via LDS
// broadcasts (float4 when CIN%4==0). Ascending-c fp32 -> bitwise identical.
template<int CIN>
__global__ __launch_bounds__(256) void gemmG_kernel(const float* __restrict__ xin,
                                                    const float* __restrict__ w1,
                                                    float* __restrict__ G) {
    __shared__ __align__(16) float xr[16][CIN];
    const int bn0 = blockIdx.x * 16;
    const int tid = threadIdx.x;
    for (int p = tid; p < 16 * CIN; p += 256)
        xr[p / CIN][p % CIN] = xin[(size_t)bn0 * CIN + p];
    const int h = tid & 63, rgrp = tid >> 6;
    float wcol[CIN];
    #pragma unroll
    for (int c = 0; c < CIN; ++c) wcol[c] = w1[(CIN + c) * 64 + h];
    __syncthreads();
    #pragma unroll
    for (int rq = 0; rq < 4; ++rq) {
        const int rr = rgrp + rq * 4;
        float a = 0.f;
        if constexpr (CIN % 4 == 0) {
            #pragma unroll
            for (int c4 = 0; c4 < CIN / 4; ++c4) {
                float4 hv = *(const float4*)&xr[rr][c4 * 4];
                a += hv.x * wcol[c4 * 4 + 0];
                a += hv.y * wcol[c4 * 4 + 1];
                a += hv.z * wcol[c4 * 4 + 2];
                a += hv.w * wcol[c4 * 4 + 3];
            }
        } else {
            #pragma unroll
            for (int c = 0; c < CIN; ++c) a += xr[rr][c] * wcol[c];
        }
        G[(size_t)(bn0 + rr) * 64 + h] = a;
    }
}

// ---------------------------------------------------------------- EdgeConv v4: G-decomposed, weights in regs
// v4: phase-1 weight column w1col[CIN] in VGPRs from global (coalesced over h,
// L2-resident) instead of 16KB w1us LDS staging + spread reads. Block LDS drops
// ~41.5KB -> ~25.5KB (3 -> 6 blocks/CU). Accumulation order unchanged.
template<int CIN, int COUT, bool BF16OUT>
__global__ __launch_bounds__(256) void edgeconv3_kernel(
        const float* __restrict__ xin, const u16* __restrict__ knn,
        const float* __restrict__ w1, const float* __restrict__ b1,
        const float* __restrict__ w2, const float* __restrict__ b2,
        const float* __restrict__ G, void* __restrict__ out) {
    constexpr int SPLIT = 256 / COUT;      // 2 for COUT=128, 4 for COUT=64
    constexpr int KPS = KK / SPLIT;        // 10 / 5
    const int bn0 = blockIdx.x * 4;
    const int b = bn0 >> 11;
    const int tid = threadIdx.x;
    __shared__ __align__(16) float xr[4][CIN];
    __shared__ __align__(16) float h1s[4][KK][64];
    __shared__ float pms[4][SPLIT][COUT];
    __shared__ int js[4][KK];

    for (int p = tid; p < 4 * CIN; p += 256)
        xr[p / CIN][p % CIN] = xin[(size_t)bn0 * CIN + p];
    if (tid < 4 * KK) {
        int j = knn[(size_t)(bn0 + tid / KK) * KK + (tid % KK)];
        js[tid / KK][tid % KK] = (j < NN) ? j : 0;
    }
    __syncthreads();

    // phase 1: h1[pp][k][h]; W1-upper column in registers
    {
        const int pp = tid >> 6, h = tid & 63;
        float w1col[CIN];
        #pragma unroll
        for (int c = 0; c < CIN; ++c) w1col[c] = w1[c * 64 + h];
        float u = b1[h];
        if constexpr (CIN % 4 == 0) {
            #pragma unroll
            for (int c4 = 0; c4 < CIN / 4; ++c4) {
                float4 hv = *(const float4*)&xr[pp][c4 * 4];
                u += hv.x * w1col[c4 * 4 + 0];
                u += hv.y * w1col[c4 * 4 + 1];
                u += hv.z * w1col[c4 * 4 + 2];
                u += hv.w * w1col[c4 * 4 + 3];
            }
        } else {
            #pragma unroll
            for (int c = 0; c < CIN; ++c) u += xr[pp][c] * w1col[c];
        }
        u -= G[(size_t)(bn0 + pp) * 64 + h];
        const float* Gb = G + (size_t)b * NN * 64 + h;
        for (int k = 0; k < KK; ++k) {
            float gj = Gb[(size_t)js[pp][k] * 64];
            h1s[pp][k][h] = fmaxf(u + gj, 0.f);
        }
    }
    __syncthreads();

    // phase 2: layer2, W2 column in registers
    {
        const int o = tid % COUT, ks = tid / COUT;
        float wcol[64];
        #pragma unroll
        for (int c = 0; c < 64; ++c) wcol[c] = w2[c * COUT + o];
        #pragma unroll
        for (int pp = 0; pp < 4; ++pp) {
            float mx = -INFINITY;
            for (int k = ks * KPS; k < (ks + 1) * KPS; ++k) {
                float acc = 0.f;
                #pragma unroll
                for (int c4 = 0; c4 < 16; ++c4) {
                    float4 hv = *(const float4*)&h1s[pp][k][c4 * 4];
                    acc += hv.x * wcol[c4 * 4 + 0];
                    acc += hv.y * wcol[c4 * 4 + 1];
                    acc += hv.z * wcol[c4 * 4 + 2];
                    acc += hv.w * wcol[c4 * 4 + 3];
                }
                mx = fmaxf(mx, acc);
            }
            pms[pp][ks][o] = mx;
        }
    }
    __syncthreads();
    for (int idx = tid; idx < 4 * COUT; idx += 256) {
        int pp = idx / COUT, oo = idx % COUT;
        float mx = pms[pp][0][oo];
        #pragma unroll
        for (int s2 = 1; s2 < SPLIT; ++s2) mx = fmaxf(mx, pms[pp][s2][oo]);
        mx += b2[oo];
        if (BF16OUT) ((bf16*)out)[(size_t)(bn0 + pp) * COUT + oo] = __float2bfloat16(mx);
        else         ((float*)out)[(size_t)(bn0 + pp) * COUT + oo] = mx;
    }
}

// ---------------------------------------------------------------- global max over N (2-stage)
__global__ __launch_bounds__(128) void gmax1_kernel(const bf16* __restrict__ f2,
                                                    float* __restrict__ pmax) {
    const int b = blockIdx.x >> 4, ch = blockIdx.x & 15, c = threadIdx.x;
    float m = -INFINITY;
    const bf16* base = f2 + ((size_t)(b * NN + ch * 128)) * 128 + c;
    for (int n = 0; n < 128; ++n) m = fmaxf(m, b2f(base[(size_t)n * 128]));
    pmax[blockIdx.x * 128 + c] = m;
}

__global__ __launch_bounds__(128) void gmax2_kernel(const float* __restrict__ pmax,
                                                    float* __restrict__ glob) {
    const int b = blockIdx.x, c = threadIdx.x;
    float m = -INFINITY;
    for (int ch = 0; ch < 16; ++ch) m = fmaxf(m, pmax[(b * 16 + ch) * 128 + c]);
    glob[b * 128 + c] = m;
}

// ---------------------------------------------------------------- K + V^T for all heads (v2)
__global__ __launch_bounds__(256) void kvt_kernel(const bf16* __restrict__ f2,
                                                  const float* __restrict__ qkv_w,
                                                  bf16* __restrict__ kk,
                                                  bf16* __restrict__ vt) {
    const int blk = blockIdx.x;            // 4 * (BBNN/16)
    const int h = blk >> 10;
    const int rg = blk & 1023;
    const int bn0 = rg * 16;
    const int b = bn0 >> 11, n0 = bn0 & 2047;
    const int tid = threadIdx.x;
    __shared__ __align__(16) float f2s[16][128];
    __shared__ float vbuf[16][32];

    for (int p = tid; p < 16 * 128; p += 256) {
        int rr = p >> 7, c = p & 127;
        f2s[rr][c] = b2f(f2[(size_t)(bn0 + rr) * 128 + c]);
    }
    const int col = tid & 63, rgrp = tid >> 6;     // col = kv*32+d
    const int kv = col >> 5, d = col & 31;
    float wcol[128];
    #pragma unroll
    for (int c = 0; c < 128; ++c)
        wcol[c] = qkv_w[c * 384 + 128 + kv * 128 + h * 32 + d];
    __syncthreads();

    #pragma unroll
    for (int rq = 0; rq < 4; ++rq) {
        const int rr = rgrp + rq * 4;
        float acc = 0.f;
        #pragma unroll
        for (int c4 = 0; c4 < 32; ++c4) {
            float4 hv = *(const float4*)&f2s[rr][c4 * 4];
            acc += hv.x * wcol[c4 * 4 + 0];
            acc += hv.y * wcol[c4 * 4 + 1];
            acc += hv.z * wcol[c4 * 4 + 2];
            acc += hv.w * wcol[c4 * 4 + 3];
        }
        if (kv == 0)
            kk[((size_t)(b * 4 + h) * 2048 + n0 + rr) * 32 + d] = __float2bfloat16(acc);
        else
            vbuf[rr][d] = acc;
    }
    __syncthreads();
    if (tid < 128) {
        int dd = tid >> 2, r2 = tid & 3;
        #pragma unroll
        for (int rq = 0; rq < 4; ++rq) {
            int r = r2 + rq * 4;
            vt[((size_t)(b * 4 + h) * 32 + dd) * 2048 + n0 + r] = __float2bfloat16(vbuf[r][dd]);
        }
    }
}

// ---------------------------------------------------------------- MFMA flash attention (v2: wave-local pbuf, barriers removed)
__global__ __launch_bounds__(256) void attn_mfma_kernel(
        const bf16* __restrict__ f2, const float* __restrict__ qkv_w,
        const bf16* __restrict__ kk, const bf16* __restrict__ vt,
        bf16* __restrict__ atth) {
    const int blk = blockIdx.x;
    const int tile = blk & 31;
    const int h = (blk >> 5) & 3;
    const int b = blk >> 7;
    const int tid = threadIdx.x;
    const int w = tid >> 6;
    const int lane = tid & 63;
    const int lq = lane & 15;
    const int quad = lane >> 4;
    const float scale = 0.17677669529663687f;

    __shared__ __align__(16) bf16 WqT[32][128];
    __shared__ __align__(16) bf16 pbuf[4][2][16][32];

    for (int p = tid; p < 4096; p += 256) {
        int c = p >> 5, d = p & 31;
        WqT[d][c] = __float2bfloat16(qkv_w[c * 384 + h * 32 + d]);
    }
    __syncthreads();   // real cross-wave dependency (WqT)

    const int q0 = tile * 64 + w * 16;
    const bf16* fbase = f2 + ((size_t)(b * NN + q0 + lq)) * 128;
    f32x4 qc0 = {0.f, 0.f, 0.f, 0.f}, qc1 = {0.f, 0.f, 0.f, 0.f};
    #pragma unroll
    for (int kc = 0; kc < 4; ++kc) {
        short8 af = *(const short8*)(fbase + kc * 32 + quad * 8);
        short8 b0 = *(const short8*)(&WqT[lq][kc * 32 + quad * 8]);
        short8 b1 = *(const short8*)(&WqT[16 + lq][kc * 32 + quad * 8]);
        qc0 = __builtin_amdgcn_mfma_f32_16x16x32_bf16(af, b0, qc0, 0, 0, 0);
        qc1 = __builtin_amdgcn_mfma_f32_16x16x32_bf16(af, b1, qc1, 0, 0, 0);
    }
    {
        bf16* pw = &pbuf[w][0][0][0];
        #pragma unroll
        for (int r = 0; r < 4; ++r) {
            int qq = quad * 4 + r;
            pw[qq * 32 + lq]      = __float2bfloat16(qc0[r] * scale);
            pw[qq * 32 + 16 + lq] = __float2bfloat16(qc1[r] * scale);
        }
    }
    // same-wave LDS RAW: in-order DS pipeline + compiler lgkmcnt; no barrier
    const short8 qfrag = *(const short8*)(&pbuf[w][0][lq][quad * 8]);

    const bf16* kb = kk + (size_t)(b * 4 + h) * 2048 * 32;
    const bf16* vb = vt + (size_t)(b * 4 + h) * 32 * 2048;
    f32x4 o0 = {0.f, 0.f, 0.f, 0.f}, o1 = {0.f, 0.f, 0.f, 0.f};
    f32x4 lsum = {0.f, 0.f, 0.f, 0.f};
    const short8 ones = {(short)0x3F80, (short)0x3F80, (short)0x3F80, (short)0x3F80,
                         (short)0x3F80, (short)0x3F80, (short)0x3F80, (short)0x3F80};

    for (int ch = 0; ch < 64; ++ch) {
        const int j0 = ch * 32;
        short8 kf0 = *(const short8*)(kb + (size_t)(j0 + lq) * 32 + quad * 8);
        short8 kf1 = *(const short8*)(kb + (size_t)(j0 + 16 + lq) * 32 + quad * 8);
        f32x4 z = {0.f, 0.f, 0.f, 0.f};
        f32x4 s0 = __builtin_amdgcn_mfma_f32_16x16x32_bf16(qfrag, kf0, z, 0, 0, 0);
        f32x4 s1 = __builtin_amdgcn_mfma_f32_16x16x32_bf16(qfrag, kf1, z, 0, 0, 0);
        bf16* pw = &pbuf[w][ch & 1][0][0];
        #pragma unroll
        for (int r = 0; r < 4; ++r) {
            int qq = quad * 4 + r;
            pw[qq * 32 + lq]      = __float2bfloat16(__expf(s0[r]));
            pw[qq * 32 + 16 + lq] = __float2bfloat16(__expf(s1[r]));
        }
        // same-wave LDS RAW (pbuf[w] only); no block barrier -> K/V loads pipeline
        short8 pf = *(const short8*)(pw + lq * 32 + quad * 8);
        short8 vf0 = *(const short8*)(vb + (size_t)lq * 2048 + j0 + quad * 8);
        short8 vf1 = *(const short8*)(vb + (size_t)(16 + lq) * 2048 + j0 + quad * 8);
        o0   = __builtin_amdgcn_mfma_f32_16x16x32_bf16(pf, vf0, o0, 0, 0, 0);
        o1   = __builtin_amdgcn_mfma_f32_16x16x32_bf16(pf, vf1, o1, 0, 0, 0);
        lsum = __builtin_amdgcn_mfma_f32_16x16x32_bf16(pf, ones, lsum, 0, 0, 0);
    }

    #pragma unroll
    for (int r = 0; r < 4; ++r) {
        int row = q0 + quad * 4 + r;
        float inv = 1.f / lsum[r];
        bf16* orow = atth + ((size_t)(b * NN + row)) * 128 + h * 32;
        orow[lq]      = __float2bfloat16(o0[r] * inv);
        orow[16 + lq] = __float2bfloat16(o1[r] * inv);
    }
}

// ---------------------------------------------------------------- fused out-proj + concat + refine MLP + log_softmax
__global__ __launch_bounds__(128) void final_kernel(
        const bf16* __restrict__ f2, const float* __restrict__ glob,
        const bf16* __restrict__ atth,
        const float* __restrict__ out_w, const float* __restrict__ out_b,
        const float* __restrict__ r1_w, const float* __restrict__ r1_b,
        const float* __restrict__ r2_w, const float* __restrict__ r2_b,
        const float* __restrict__ r3_w, const float* __restrict__ r3_b,
        float* __restrict__ out) {
    const int bn0 = blockIdx.x * 4;
    const int b = bn0 >> 11;
    const int tid = threadIdx.x;
    __shared__ float attin[4][128], comb[4][384], h1[4][128], h2[4][64];
    __shared__ float logits[4][20], lse[4];

    #pragma unroll
    for (int rr = 0; rr < 4; ++rr) {
        attin[rr][tid]      = b2f(atth[(size_t)(bn0 + rr) * 128 + tid]);
        comb[rr][tid]       = b2f(f2[(size_t)(bn0 + rr) * 128 + tid]);
        comb[rr][128 + tid] = glob[b * 128 + tid];
    }
    __syncthreads();
    {
        float a0 = 0.f, a1 = 0.f, a2 = 0.f, a3 = 0.f;
        for (int c = 0; c < 128; ++c) {
            float wv = out_w[c * 128 + tid];
            a0 += attin[0][c] * wv; a1 += attin[1][c] * wv;
            a2 += attin[2][c] * wv; a3 += attin[3][c] * wv;
        }
        float bb = out_b[tid];
        comb[0][256 + tid] = a0 + bb; comb[1][256 + tid] = a1 + bb;
        comb[2][256 + tid] = a2 + bb; comb[3][256 + tid] = a3 + bb;
    }
    __syncthreads();
    {
        float a0 = 0.f, a1 = 0.f, a2 = 0.f, a3 = 0.f;
        for (int c = 0; c < 384; ++c) {
            float wv = r1_w[c * 128 + tid];
            a0 += comb[0][c] * wv; a1 += comb[1][c] * wv;
            a2 += comb[2][c] * wv; a3 += comb[3][c] * wv;
        }
        float bb = r1_b[tid];
        h1[0][tid] = fmaxf(a0 + bb, 0.f); h1[1][tid] = fmaxf(a1 + bb, 0.f);
        h1[2][tid] = fmaxf(a2 + bb, 0.f); h1[3][tid] = fmaxf(a3 + bb, 0.f);
    }
    __syncthreads();
    if (tid < 64) {
        float a0 = 0.f, a1 = 0.f, a2 = 0.f, a3 = 0.f;
        for (int c = 0; c < 128; ++c) {
            float wv = r2_w[c * 64 + tid];
            a0 += h1[0][c] * wv; a1 += h1[1][c] * wv;
            a2 += h1[2][c] * wv; a3 += h1[3][c] * wv;
        }
        float bb = r2_b[tid];
        h2[0][tid] = fmaxf(a0 + bb, 0.f); h2[1][tid] = fmaxf(a1 + bb, 0.f);
        h2[2][tid] = fmaxf(a2 + bb, 0.f); h2[3][tid] = fmaxf(a3 + bb, 0.f);
    }
    __syncthreads();
    if (tid < 20) {
        float a0 = 0.f, a1 = 0.f, a2 = 0.f, a3 = 0.f;
        for (int c = 0; c < 64; ++c) {
            float wv = r3_w[c * 20 + tid];
            a0 += h2[0][c] * wv; a1 += h2[1][c] * wv;
            a2 += h2[2][c] * wv; a3 += h2[3][c] * wv;
        }
        float bb = r3_b[tid];
        logits[0][tid] = a0 + bb; logits[1][tid] = a1 + bb;
        logits[2][tid] = a2 + bb; logits[3][tid] = a3 + bb;
    }
    __syncthreads();
    if (tid < 4) {
        float m = -INFINITY;
        for (int u = 0; u < 20; ++u) m = fmaxf(m, logits[tid][u]);
        float s = 0.f;
        for (int u = 0; u < 20; ++u) s += expf(logits[tid][u] - m);
        lse[tid] = m + logf(s);
    }
    __syncthreads();
    if (tid < 80) {
        int rr = tid / 20, cls = tid % 20;
        out[(size_t)(bn0 + rr) * 20 + cls] = logits[rr][cls] - lse[rr];
    }
}

// ----------------------------------------------------------------------------
// Layout (ws >= NEED_A = 16,846,848 B — proven: Path A ran in round 10):
//   [0,4M)       f1T (phases 1-3) -> f2 bf16 (phase 3+)
//   [4M,+64K)    sqb | [4M+64K,8M+64K) f1 | [8M+64K,+640K) knn | +192K xT3
//   [4M,8M)      kkA (after ec2; f1/sqb dead) | [8M,12M) vtA
//   [12M,16M)    G (gemmG scratch, phases 1-3) -> atth (attention phase)
//   [16M,+68K)   pmax | glob
extern "C" void kernel_launch(void* const* d_in, const int* in_sizes, int n_in,
                              void* d_out, int out_size, void* d_ws, size_t ws_size,
                              hipStream_t stream) {
    const float* x      = (const float*)d_in[0];
    const float* ec1_w1 = (const float*)d_in[2];
    const float* ec1_b1 = (const float*)d_in[3];
    const float* ec1_w2 = (const float*)d_in[4];
    const float* ec1_b2 = (const float*)d_in[5];
    const float* ec2_w1 = (const float*)d_in[6];
    const float* ec2_b1 = (const float*)d_in[7];
    const float* ec2_w2 = (const float*)d_in[8];
    const float* ec2_b2 = (const float*)d_in[9];
    const float* qkv_w  = (const float*)d_in[10];
    const float* out_w  = (const float*)d_in[11];
    const float* out_b  = (const float*)d_in[12];
    const float* r1_w   = (const float*)d_in[13];
    const float* r1_b   = (const float*)d_in[14];
    const float* r2_w   = (const float*)d_in[15];
    const float* r2_b   = (const float*)d_in[16];
    const float* r3_w   = (const float*)d_in[17];
    const float* r3_b   = (const float*)d_in[18];
    float* out = (float*)d_out;

    const size_t MB = 1024 * 1024;
    const size_t NEED_A = 16 * MB + 65536 + 4096;
    if (ws_size < NEED_A) return;   // guard (clean numeric fail, not a fault)

    char* base = (char*)d_ws;
    bf16*  f2   = (bf16*)(base);
    float* f1T  = (float*)(base);
    float* sqb  = (float*)(base + 4 * MB);
    float* f1   = (float*)(base + 4 * MB + 65536);
    u16*   knn  = (u16*)(base + 8 * MB + 65536);
    float* xT3  = (float*)(base + 8 * MB + 65536 + 655360);
    float* G    = (float*)(base + 12 * MB);           // phases 1-3
    bf16*  kkA  = (bf16*)(base + 4 * MB);             // attention phase
    bf16*  vtA  = (bf16*)(base + 8 * MB);
    bf16*  atth = (bf16*)(base + 12 * MB);
    float* pmax = (float*)(base + 16 * MB);
    float* glob = (float*)(base + 16 * MB + 65536);

    sqT_kernel<3><<<BBNN / 256, 256, 0, stream>>>(x, sqb, xT3);
    knn1_kernel<3><<<BB * 256, 512, 0, stream>>>(x, xT3, sqb, knn);
    gemmG_kernel<3><<<BBNN / 16, 256, 0, stream>>>(x, ec1_w1, G);
    edgeconv3_kernel<3, 64, false><<<BBNN / 4, 256, 0, stream>>>(
        x, knn, ec1_w1, ec1_b1, ec1_w2, ec1_b2, G, f1);

    sqT_kernel<64><<<BBNN / 256, 256, 0, stream>>>(f1, sqb, f1T);
    knn_fast_kernel<64, 8><<<BB * 128, 512, 0, stream>>>(f1, f1T, sqb, knn);
    gemmG_kernel<64><<<BBNN / 16, 256, 0, stream>>>(f1, ec2_w1, G);
    edgeconv3_kernel<64, 128, true><<<BBNN / 4, 256, 0, stream>>>(
        f1, knn, ec2_w1, ec2_b1, ec2_w2, ec2_b2, G, f2);

    gmax1_kernel<<<BB * 16, 128, 0, stream>>>(f2, pmax);
    gmax2_kernel<<<BB, 128, 0, stream>>>(pmax, glob);

    kvt_kernel<<<4 * BBNN / 16, 256, 0, stream>>>(f2, qkv_w, kkA, vtA);
    attn_mfma_kernel<<<BB * 4 * 32, 256, 0, stream>>>(f2, qkv_w, kkA, vtA, atth);

    final_kernel<<<BBNN / 4, 128, 0, stream>>>(
        f2, glob, atth, out_w, out_b, r1_w, r1_b, r2_w, r2_b, r3_w, r3_b, out);
}

// Round 16
// 684.411 us; speedup vs baseline: 1.1345x; 1.0496x over previous
//
#include <hip/hip_runtime.h>
#include <hip/hip_bf16.h>

#define BB 8
#define NN 2048
#define KK 20
#define BBNN (BB * NN)

typedef __hip_bfloat16 bf16;
typedef unsigned short u16;
typedef __attribute__((ext_vector_type(8))) short short8;
typedef __attribute__((ext_vector_type(4))) float f32x4;

__device__ __forceinline__ float b2f(bf16 v) { return __bfloat162float(v); }

// ---------------------------------------------------------------- sq + transpose (fused)
template<int C>
__global__ __launch_bounds__(256) void sqT_kernel(const float* __restrict__ xin,
                                                  float* __restrict__ sq,
                                                  float* __restrict__ xT) {
    int t = blockIdx.x * 256 + threadIdx.x;
    if (t >= BBNN) return;
    const float* p = xin + (size_t)t * C;
    float s = 0.f;
    for (int c = 0; c < C; ++c) {
        float v = p[c];
        s += v * v;
        xT[(size_t)c * BBNN + t] = v;
    }
    sq[t] = s;
}

// ---------------------------------------------------------------- kNN, 1 query/wave (for C=3)
template<int C>
__global__ __launch_bounds__(512, 4) void knn1_kernel(
        const float* __restrict__ xrows,
        const float* __restrict__ xT,
        const float* __restrict__ sq,
        u16* __restrict__ idx_out) {
    __shared__ __align__(16) float xs[C][2048];
    const int blk = blockIdx.x;            // BB * 256
    const int b = blk >> 8;
    const int tile = blk & 255;
    const int w = threadIdx.x >> 6;
    const int s = threadIdx.x & 63;
    const int tid = threadIdx.x;
    const int iA = tile * 8 + w;
    const int bn0 = b * NN;

    float dA[32];
    #pragma unroll
    for (int r = 0; r < 32; ++r) dA[r] = 0.f;

    for (int u = tid; u < C * 512; u += 512) {
        int row = u / 512, c4 = u % 512;
        *(float4*)&xs[row][c4 * 4] =
            *(const float4*)(xT + (size_t)row * BBNN + bn0 + c4 * 4);
    }
    __syncthreads();

    const int qbase = __builtin_amdgcn_readfirstlane((bn0 + iA) * C);
    float xq[C];
    #pragma unroll
    for (int cc = 0; cc < C; ++cc) xq[cc] = xrows[qbase + cc];

    #pragma unroll
    for (int t = 0; t < 8; ++t) {
        float a0 = 0.f, a1 = 0.f, a2 = 0.f, a3 = 0.f;
        #pragma unroll
        for (int cc = 0; cc < C; ++cc) {
            float4 xv = *(const float4*)&xs[cc][t * 256 + s * 4];
            float q = xq[cc];
            a0 += q * xv.x; a1 += q * xv.y; a2 += q * xv.z; a3 += q * xv.w;
        }
        dA[t * 4 + 0] += a0; dA[t * 4 + 1] += a1;
        dA[t * 4 + 2] += a2; dA[t * 4 + 3] += a3;
    }
    const float sqi = sq[bn0 + iA];
    #pragma unroll
    for (int r = 0; r < 32; ++r) {
        int j = ((r >> 2) << 8) + (s << 2) + (r & 3);
        dA[r] = (sqi + sq[bn0 + j]) - 2.f * dA[r];
    }

    unsigned rm = 0u;
    float m1 = INFINITY, m2 = INFINITY;
    int j1 = 0x7fffffff, j2 = 0x7fffffff;
    #pragma unroll
    for (int r = 0; r < 32; ++r) {
        int j = ((r >> 2) << 8) + (s << 2) + (r & 3);
        float d = dA[r];
        bool l1 = d < m1, l2 = d < m2;
        m2 = l1 ? m1 : (l2 ? d : m2);
        j2 = l1 ? j1 : (l2 ? j : j2);
        m1 = l1 ? d : m1;  j1 = l1 ? j : j1;
    }
    for (int k = 0; k < KK; ++k) {
        if (__any(j1 < 0)) {
            if (j1 < 0) {
                m1 = INFINITY; m2 = INFINITY; j1 = 0x7fffffff; j2 = 0x7fffffff;
                #pragma unroll
                for (int r = 0; r < 32; ++r) {
                    int j = ((r >> 2) << 8) + (s << 2) + (r & 3);
                    float d = (rm & (1u << r)) ? INFINITY : dA[r];
                    bool l1 = d < m1, l2 = d < m2;
                    m2 = l1 ? m1 : (l2 ? d : m2);
                    j2 = l1 ? j1 : (l2 ? j : j2);
                    m1 = l1 ? d : m1;  j1 = l1 ? j : j1;
                }
            }
        }
        float rd = m1; int rj = j1;
        #pragma unroll
        for (int m = 1; m < 64; m <<= 1) {
            float od = __shfl_xor(rd, m); int oj = __shfl_xor(rj, m);
            if (od < rd || (od == rd && oj < rj)) { rd = od; rj = oj; }
        }
        if (s == 0) idx_out[(size_t)(bn0 + iA) * KK + k] = (u16)rj;
        if (k + 1 < KK) {
            if (s == ((rj >> 2) & 63)) {
                int rr = ((rj >> 8) << 2) + (rj & 3);
                rm |= (1u << rr);
                m1 = m2; j1 = j2; m2 = INFINITY; j2 = -1;
            }
        }
    }
}

// ---------------------------------------------------------------- fast kNN v12 (C=64; structural floor)
template<int C, int CH>
__global__ __launch_bounds__(512, 4) void knn_fast_kernel(
        const float* __restrict__ xrows,
        const float* __restrict__ xT,
        const float* __restrict__ sq,
        u16* __restrict__ idx_out) {
    __shared__ __align__(16) float xs[CH][2048];
    const int blk = blockIdx.x;            // BB * 128
    const int b = blk >> 7;
    const int tile = blk & 127;
    const int w = threadIdx.x >> 6;
    const int s = threadIdx.x & 63;
    const int iA = tile * 16 + w * 2;
    const int bn0 = b * NN;
    constexpr int NCH = C / CH;            // 8 for <64,8>

    float dA[32], dB[32];
    #pragma unroll
    for (int r = 0; r < 32; ++r) { dA[r] = 0.f; dB[r] = 0.f; }

    const int qbase = __builtin_amdgcn_readfirstlane((bn0 + iA) * C);

    for (int ch = 0; ch < NCH; ++ch) {
        __syncthreads();   // WAR guard vs previous phase's readers
        for (int u = threadIdx.x; u < CH * 512; u += 512) {
            int row = u >> 9, c4 = u & 511;
            *(float4*)&xs[row][c4 * 4] =
                *(const float4*)(xT + (size_t)(ch * CH + row) * BBNN + bn0 + c4 * 4);
        }
        __syncthreads();
        float xqA[CH], xqB[CH];            // wave-uniform -> scalar loads
        #pragma unroll
        for (int cc = 0; cc < CH; ++cc) {
            xqA[cc] = xrows[qbase + ch * CH + cc];
            xqB[cc] = xrows[qbase + C + ch * CH + cc];
        }
        #pragma unroll
        for (int t = 0; t < 8; ++t) {      // unrolled -> dA/dB indices static
            float aA0 = 0.f, aA1 = 0.f, aA2 = 0.f, aA3 = 0.f;
            float aB0 = 0.f, aB1 = 0.f, aB2 = 0.f, aB3 = 0.f;
            #pragma unroll
            for (int cc = 0; cc < CH; ++cc) {
                float4 xv = *(const float4*)&xs[cc][t * 256 + s * 4];
                float qA = xqA[cc], qB = xqB[cc];
                aA0 += qA * xv.x; aA1 += qA * xv.y; aA2 += qA * xv.z; aA3 += qA * xv.w;
                aB0 += qB * xv.x; aB1 += qB * xv.y; aB2 += qB * xv.z; aB3 += qB * xv.w;
            }
            dA[t * 4 + 0] += aA0; dA[t * 4 + 1] += aA1;
            dA[t * 4 + 2] += aA2; dA[t * 4 + 3] += aA3;
            dB[t * 4 + 0] += aB0; dB[t * 4 + 1] += aB1;
            dB[t * 4 + 2] += aB2; dB[t * 4 + 3] += aB3;
        }
    }
    const float sqiA = sq[bn0 + iA];
    const float sqiB = sq[bn0 + iA + 1];
    #pragma unroll
    for (int r = 0; r < 32; ++r) {
        int j = ((r >> 2) << 8) + (s << 2) + (r & 3);
        float sqj = sq[bn0 + j];
        dA[r] = (sqiA + sqj) - 2.f * dA[r];
        dB[r] = (sqiB + sqj) - 2.f * dB[r];
    }

    // ---- selection: interleaved A/B, per-lane top-2 cache, removal bitmask ----
    unsigned rmA = 0u, rmB = 0u;           // removed-candidate bits (per lane)
    float m1A = INFINITY, m2A = INFINITY, m1B = INFINITY, m2B = INFINITY;
    int j1A = 0x7fffffff, j2A = 0x7fffffff, j1B = 0x7fffffff, j2B = 0x7fffffff;
    #pragma unroll
    for (int r = 0; r < 32; ++r) {
        int j = ((r >> 2) << 8) + (s << 2) + (r & 3);
        float d = dA[r];
        bool l1 = d < m1A, l2 = d < m2A;
        m2A = l1 ? m1A : (l2 ? d : m2A);
        j2A = l1 ? j1A : (l2 ? j : j2A);
        m1A = l1 ? d : m1A;  j1A = l1 ? j : j1A;
        d = dB[r];
        l1 = d < m1B; l2 = d < m2B;
        m2B = l1 ? m1B : (l2 ? d : m2B);
        j2B = l1 ? j1B : (l2 ? j : j2B);
        m1B = l1 ? d : m1B;  j1B = l1 ? j : j1B;
    }

    for (int k = 0; k < KK; ++k) {
        // refill lanes whose m1 went invalid (won twice since last scan)
        if (__any(j1A < 0)) {
            if (j1A < 0) {
                m1A = INFINITY; m2A = INFINITY; j1A = 0x7fffffff; j2A = 0x7fffffff;
                #pragma unroll
                for (int r = 0; r < 32; ++r) {
                    int j = ((r >> 2) << 8) + (s << 2) + (r & 3);
                    float d = (rmA & (1u << r)) ? INFINITY : dA[r];
                    bool l1 = d < m1A, l2 = d < m2A;
                    m2A = l1 ? m1A : (l2 ? d : m2A);
                    j2A = l1 ? j1A : (l2 ? j : j2A);
                    m1A = l1 ? d : m1A;  j1A = l1 ? j : j1A;
                }
            }
        }
        if (__any(j1B < 0)) {
            if (j1B < 0) {
                m1B = INFINITY; m2B = INFINITY; j1B = 0x7fffffff; j2B = 0x7fffffff;
                #pragma unroll
                for (int r = 0; r < 32; ++r) {
                    int j = ((r >> 2) << 8) + (s << 2) + (r & 3);
                    float d = (rmB & (1u << r)) ? INFINITY : dB[r];
                    bool l1 = d < m1B, l2 = d < m2B;
                    m2B = l1 ? m1B : (l2 ? d : m2B);
                    j2B = l1 ? j1B : (l2 ? j : j2B);
                    m1B = l1 ? d : m1B;  j1B = l1 ? j : j1B;
                }
            }
        }
        // interleaved 64-lane argmin butterflies (independent chains)
        float rdA = m1A, rdB = m1B; int rjA = j1A, rjB = j1B;
        #pragma unroll
        for (int m = 1; m < 64; m <<= 1) {
            float odA = __shfl_xor(rdA, m); int ojA = __shfl_xor(rjA, m);
            float odB = __shfl_xor(rdB, m); int ojB = __shfl_xor(rjB, m);
            if (odA < rdA || (odA == rdA && ojA < rjA)) { rdA = odA; rjA = ojA; }
            if (odB < rdB || (odB == rdB && ojB < rjB)) { rdB = odB; rjB = ojB; }
        }
        if (s == 0) {
            idx_out[(size_t)(bn0 + iA) * KK + k]     = (u16)rjA;
            idx_out[(size_t)(bn0 + iA + 1) * KK + k] = (u16)rjB;
        }
        if (k + 1 < KK) {
            if (s == ((rjA >> 2) & 63)) {
                int rr = ((rjA >> 8) << 2) + (rjA & 3);
                rmA |= (1u << rr);
                m1A = m2A; j1A = j2A; m2A = INFINITY; j2A = -1;
            }
            if (s == ((rjB >> 2) & 63)) {
                int rr = ((rjB >> 8) << 2) + (rjB & 3);
                rmB |= (1u << rr);
                m1B = m2B; j1B = j2B; m2B = INFINITY; j2B = -1;
            }
        }
    }
}

// ---------------------------------------------------------------- G[n][h] = x[n] . w1_lower[.][h]  (v2)
template<int CIN>
__global__ __launch_bounds__(256) void gemmG_kernel(const float* __restrict__ xin,
                                                    const float* __restrict__ w1,
                                                    float* __restrict__ G) {
    __shared__ __align__(16) float xr[16][CIN];
    const int bn0 = blockIdx.x * 16;
    const int tid = threadIdx.x;
    for (int p = tid; p < 16 * CIN; p += 256)
        xr[p / CIN][p % CIN] = xin[(size_t)bn0 * CIN + p];
    const int h = tid & 63, rgrp = tid >> 6;
    float wcol[CIN];
    #pragma unroll
    for (int c = 0; c < CIN; ++c) wcol[c] = w1[(CIN + c) * 64 + h];
    __syncthreads();
    #pragma unroll
    for (int rq = 0; rq < 4; ++rq) {
        const int rr = rgrp + rq * 4;
        float a = 0.f;
        if constexpr (CIN % 4 == 0) {
            #pragma unroll
            for (int c4 = 0; c4 < CIN / 4; ++c4) {
                float4 hv = *(const float4*)&xr[rr][c4 * 4];
                a += hv.x * wcol[c4 * 4 + 0];
                a += hv.y * wcol[c4 * 4 + 1];
                a += hv.z * wcol[c4 * 4 + 2];
                a += hv.w * wcol[c4 * 4 + 3];
            }
        } else {
            #pragma unroll
            for (int c = 0; c < CIN; ++c) a += xr[rr][c] * wcol[c];
        }
        G[(size_t)(bn0 + rr) * 64 + h] = a;
    }
}

// ---------------------------------------------------------------- EdgeConv v5: G-decomposed
// v5 change: for COUT=128, phase 2 pairs output columns (o, o+64) per thread:
// one h1s float4 read feeds 8 fmas instead of 4 -> LDS-read issue halves
// (was the binding pipe: 640 b128 reads vs 2560 fma per wave). k-split 2x10 ->
// 4x5; fmax is associative so regrouping is bitwise-identical; per-column dot
// order unchanged. wcol 128 regs = proven kvt-v2 footprint.
template<int CIN, int COUT, bool BF16OUT>
__global__ __launch_bounds__(256) void edgeconv3_kernel(
        const float* __restrict__ xin, const u16* __restrict__ knn,
        const float* __restrict__ w1, const float* __restrict__ b1,
        const float* __restrict__ w2, const float* __restrict__ b2,
        const float* __restrict__ G, void* __restrict__ out) {
    constexpr int NS = 4;                  // k-splits (KPS=5) for both COUT
    constexpr int KPS = KK / NS;
    const int bn0 = blockIdx.x * 4;
    const int b = bn0 >> 11;
    const int tid = threadIdx.x;
    __shared__ __align__(16) float xr[4][CIN];
    __shared__ __align__(16) float h1s[4][KK][64];
    __shared__ float pms[4][NS][COUT];
    __shared__ int js[4][KK];

    for (int p = tid; p < 4 * CIN; p += 256)
        xr[p / CIN][p % CIN] = xin[(size_t)bn0 * CIN + p];
    if (tid < 4 * KK) {
        int j = knn[(size_t)(bn0 + tid / KK) * KK + (tid % KK)];
        js[tid / KK][tid % KK] = (j < NN) ? j : 0;
    }
    __syncthreads();

    // phase 1: h1[pp][k][h]; W1-upper column in registers
    {
        const int pp = tid >> 6, h = tid & 63;
        float w1col[CIN];
        #pragma unroll
        for (int c = 0; c < CIN; ++c) w1col[c] = w1[c * 64 + h];
        float u = b1[h];
        if constexpr (CIN % 4 == 0) {
            #pragma unroll
            for (int c4 = 0; c4 < CIN / 4; ++c4) {
                float4 hv = *(const float4*)&xr[pp][c4 * 4];
                u += hv.x * w1col[c4 * 4 + 0];
                u += hv.y * w1col[c4 * 4 + 1];
                u += hv.z * w1col[c4 * 4 + 2];
                u += hv.w * w1col[c4 * 4 + 3];
            }
        } else {
            #pragma unroll
            for (int c = 0; c < CIN; ++c) u += xr[pp][c] * w1col[c];
        }
        u -= G[(size_t)(bn0 + pp) * 64 + h];
        const float* Gb = G + (size_t)b * NN * 64 + h;
        for (int k = 0; k < KK; ++k) {
            float gj = Gb[(size_t)js[pp][k] * 64];
            h1s[pp][k][h] = fmaxf(u + gj, 0.f);
        }
    }
    __syncthreads();

    // phase 2: layer2, W2 column(s) in registers
    if constexpr (COUT == 128) {
        const int o = tid & 63, ks = tid >> 6;     // 4 splits x 64 col-pairs
        float wcolA[64], wcolB[64];
        #pragma unroll
        for (int c = 0; c < 64; ++c) {
            wcolA[c] = w2[c * COUT + o];
            wcolB[c] = w2[c * COUT + o + 64];
        }
        #pragma unroll
        for (int pp = 0; pp < 4; ++pp) {
            float mxA = -INFINITY, mxB = -INFINITY;
            for (int k = ks * KPS; k < (ks + 1) * KPS; ++k) {
                float accA = 0.f, accB = 0.f;
                #pragma unroll
                for (int c4 = 0; c4 < 16; ++c4) {
                    float4 hv = *(const float4*)&h1s[pp][k][c4 * 4];
                    accA += hv.x * wcolA[c4 * 4 + 0];
                    accA += hv.y * wcolA[c4 * 4 + 1];
                    accA += hv.z * wcolA[c4 * 4 + 2];
                    accA += hv.w * wcolA[c4 * 4 + 3];
                    accB += hv.x * wcolB[c4 * 4 + 0];
                    accB += hv.y * wcolB[c4 * 4 + 1];
                    accB += hv.z * wcolB[c4 * 4 + 2];
                    accB += hv.w * wcolB[c4 * 4 + 3];
                }
                mxA = fmaxf(mxA, accA);
                mxB = fmaxf(mxB, accB);
            }
            pms[pp][ks][o] = mxA;
            pms[pp][ks][o + 64] = mxB;
        }
    } else {
        const int o = tid % COUT, ks = tid / COUT;
        float wcol[64];
        #pragma unroll
        for (int c = 0; c < 64; ++c) wcol[c] = w2[c * COUT + o];
        #pragma unroll
        for (int pp = 0; pp < 4; ++pp) {
            float mx = -INFINITY;
            for (int k = ks * KPS; k < (ks + 1) * KPS; ++k) {
                float acc = 0.f;
                #pragma unroll
                for (int c4 = 0; c4 < 16; ++c4) {
                    float4 hv = *(const float4*)&h1s[pp][k][c4 * 4];
                    acc += hv.x * wcol[c4 * 4 + 0];
                    acc += hv.y * wcol[c4 * 4 + 1];
                    acc += hv.z * wcol[c4 * 4 + 2];
                    acc += hv.w * wcol[c4 * 4 + 3];
                }
                mx = fmaxf(mx, acc);
            }
            pms[pp][ks][o] = mx;
        }
    }
    __syncthreads();
    for (int idx = tid; idx < 4 * COUT; idx += 256) {
        int pp = idx / COUT, oo = idx % COUT;
        float mx = pms[pp][0][oo];
        #pragma unroll
        for (int s2 = 1; s2 < NS; ++s2) mx = fmaxf(mx, pms[pp][s2][oo]);
        mx += b2[oo];
        if (BF16OUT) ((bf16*)out)[(size_t)(bn0 + pp) * COUT + oo] = __float2bfloat16(mx);
        else         ((float*)out)[(size_t)(bn0 + pp) * COUT + oo] = mx;
    }
}

// ---------------------------------------------------------------- global max over N (2-stage)
__global__ __launch_bounds__(128) void gmax1_kernel(const bf16* __restrict__ f2,
                                                    float* __restrict__ pmax) {
    const int b = blockIdx.x >> 4, ch = blockIdx.x & 15, c = threadIdx.x;
    float m = -INFINITY;
    const bf16* base = f2 + ((size_t)(b * NN + ch * 128)) * 128 + c;
    for (int n = 0; n < 128; ++n) m = fmaxf(m, b2f(base[(size_t)n * 128]));
    pmax[blockIdx.x * 128 + c] = m;
}

__global__ __launch_bounds__(128) void gmax2_kernel(const float* __restrict__ pmax,
                                                    float* __restrict__ glob) {
    const int b = blockIdx.x, c = threadIdx.x;
    float m = -INFINITY;
    for (int ch = 0; ch < 16; ++ch) m = fmaxf(m, pmax[(b * 16 + ch) * 128 + c]);
    glob[b * 128 + c] = m;
}

// ---------------------------------------------------------------- K + V^T for all heads (v2)
__global__ __launch_bounds__(256) void kvt_kernel(const bf16* __restrict__ f2,
                                                  const float* __restrict__ qkv_w,
                                                  bf16* __restrict__ kk,
                                                  bf16* __restrict__ vt) {
    const int blk = blockIdx.x;            // 4 * (BBNN/16)
    const int h = blk >> 10;
    const int rg = blk & 1023;
    const int bn0 = rg * 16;
    const int b = bn0 >> 11, n0 = bn0 & 2047;
    const int tid = threadIdx.x;
    __shared__ __align__(16) float f2s[16][128];
    __shared__ float vbuf[16][32];

    for (int p = tid; p < 16 * 128; p += 256) {
        int rr = p >> 7, c = p & 127;
        f2s[rr][c] = b2f(f2[(size_t)(bn0 + rr) * 128 + c]);
    }
    const int col = tid & 63, rgrp = tid >> 6;     // col = kv*32+d
    const int kv = col >> 5, d = col & 31;
    float wcol[128];
    #pragma unroll
    for (int c = 0; c < 128; ++c)
        wcol[c] = qkv_w[c * 384 + 128 + kv * 128 + h * 32 + d];
    __syncthreads();

    #pragma unroll
    for (int rq = 0; rq < 4; ++rq) {
        const int rr = rgrp + rq * 4;
        float acc = 0.f;
        #pragma unroll
        for (int c4 = 0; c4 < 32; ++c4) {
            float4 hv = *(const float4*)&f2s[rr][c4 * 4];
            acc += hv.x * wcol[c4 * 4 + 0];
            acc += hv.y * wcol[c4 * 4 + 1];
            acc += hv.z * wcol[c4 * 4 + 2];
            acc += hv.w * wcol[c4 * 4 + 3];
        }
        if (kv == 0)
            kk[((size_t)(b * 4 + h) * 2048 + n0 + rr) * 32 + d] = __float2bfloat16(acc);
        else
            vbuf[rr][d] = acc;
    }
    __syncthreads();
    if (tid < 128) {
        int dd = tid >> 2, r2 = tid & 3;
        #pragma unroll
        for (int rq = 0; rq < 4; ++rq) {
            int r = r2 + rq * 4;
            vt[((size_t)(b * 4 + h) * 32 + dd) * 2048 + n0 + r] = __float2bfloat16(vbuf[r][dd]);
        }
    }
}

// ---------------------------------------------------------------- MFMA flash attention (v2: wave-local pbuf, barriers removed)
__global__ __launch_bounds__(256) void attn_mfma_kernel(
        const bf16* __restrict__ f2, const float* __restrict__ qkv_w,
        const bf16* __restrict__ kk, const bf16* __restrict__ vt,
        bf16* __restrict__ atth) {
    const int blk = blockIdx.x;
    const int tile = blk & 31;
    const int h = (blk >> 5) & 3;
    const int b = blk >> 7;
    const int tid = threadIdx.x;
    const int w = tid >> 6;
    const int lane = tid & 63;
    const int lq = lane & 15;
    const int quad = lane >> 4;
    const float scale = 0.17677669529663687f;

    __shared__ __align__(16) bf16 WqT[32][128];
    __shared__ __align__(16) bf16 pbuf[4][2][16][32];

    for (int p = tid; p < 4096; p += 256) {
        int c = p >> 5, d = p & 31;
        WqT[d][c] = __float2bfloat16(qkv_w[c * 384 + h * 32 + d]);
    }
    __syncthreads();   // real cross-wave dependency (WqT)

    const int q0 = tile * 64 + w * 16;
    const bf16* fbase = f2 + ((size_t)(b * NN + q0 + lq)) * 128;
    f32x4 qc0 = {0.f, 0.f, 0.f, 0.f}, qc1 = {0.f, 0.f, 0.f, 0.f};
    #pragma unroll
    for (int kc = 0; kc < 4; ++kc) {
        short8 af = *(const short8*)(fbase + kc * 32 + quad * 8);
        short8 b0 = *(const short8*)(&WqT[lq][kc * 32 + quad * 8]);
        short8 b1 = *(const short8*)(&WqT[16 + lq][kc * 32 + quad * 8]);
        qc0 = __builtin_amdgcn_mfma_f32_16x16x32_bf16(af, b0, qc0, 0, 0, 0);
        qc1 = __builtin_amdgcn_mfma_f32_16x16x32_bf16(af, b1, qc1, 0, 0, 0);
    }
    {
        bf16* pw = &pbuf[w][0][0][0];
        #pragma unroll
        for (int r = 0; r < 4; ++r) {
            int qq = quad * 4 + r;
            pw[qq * 32 + lq]      = __float2bfloat16(qc0[r] * scale);
            pw[qq * 32 + 16 + lq] = __float2bfloat16(qc1[r] * scale);
        }
    }
    // same-wave LDS RAW: in-order DS pipeline + compiler lgkmcnt; no barrier
    const short8 qfrag = *(const short8*)(&pbuf[w][0][lq][quad * 8]);

    const bf16* kb = kk + (size_t)(b * 4 + h) * 2048 * 32;
    const bf16* vb = vt + (size_t)(b * 4 + h) * 32 * 2048;
    f32x4 o0 = {0.f, 0.f, 0.f, 0.f}, o1 = {0.f, 0.f, 0.f, 0.f};
    f32x4 lsum = {0.f, 0.f, 0.f, 0.f};
    const short8 ones = {(short)0x3F80, (short)0x3F80, (short)0x3F80, (short)0x3F80,
                         (short)0x3F80, (short)0x3F80, (short)0x3F80, (short)0x3F80};

    for (int ch = 0; ch < 64; ++ch) {
        const int j0 = ch * 32;
        short8 kf0 = *(const short8*)(kb + (size_t)(j0 + lq) * 32 + quad * 8);
        short8 kf1 = *(const short8*)(kb + (size_t)(j0 + 16 + lq) * 32 + quad * 8);
        f32x4 z = {0.f, 0.f, 0.f, 0.f};
        f32x4 s0 = __builtin_amdgcn_mfma_f32_16x16x32_bf16(qfrag, kf0, z, 0, 0, 0);
        f32x4 s1 = __builtin_amdgcn_mfma_f32_16x16x32_bf16(qfrag, kf1, z, 0, 0, 0);
        bf16* pw = &pbuf[w][ch & 1][0][0];
        #pragma unroll
        for (int r = 0; r < 4; ++r) {
            int qq = quad * 4 + r;
            pw[qq * 32 + lq]      = __float2bfloat16(__expf(s0[r]));
            pw[qq * 32 + 16 + lq] = __float2bfloat16(__expf(s1[r]));
        }
        // same-wave LDS RAW (pbuf[w] only); no block barrier -> K/V loads pipeline
        short8 pf = *(const short8*)(pw + lq * 32 + quad * 8);
        short8 vf0 = *(const short8*)(vb + (size_t)lq * 2048 + j0 + quad * 8);
        short8 vf1 = *(const short8*)(vb + (size_t)(16 + lq) * 2048 + j0 + quad * 8);
        o0   = __builtin_amdgcn_mfma_f32_16x16x32_bf16(pf, vf0, o0, 0, 0, 0);
        o1   = __builtin_amdgcn_mfma_f32_16x16x32_bf16(pf, vf1, o1, 0, 0, 0);
        lsum = __builtin_amdgcn_mfma_f32_16x16x32_bf16(pf, ones, lsum, 0, 0, 0);
    }

    #pragma unroll
    for (int r = 0; r < 4; ++r) {
        int row = q0 + quad * 4 + r;
        float inv = 1.f / lsum[r];
        bf16* orow = atth + ((size_t)(b * NN + row)) * 128 + h * 32;
        orow[lq]      = __float2bfloat16(o0[r] * inv);
        orow[16 + lq] = __float2bfloat16(o1[r] * inv);
    }
}

// ---------------------------------------------------------------- fused out-proj + concat + refine MLP + log_softmax (v2)
// v2: 8 rows/block (grid BBNN/8), 256 threads = 2x4-row groups using the
// IDENTICAL proven inner loops -> weight L2 traffic per row halved, 2x waves
// per block for latency hiding. Per-element accumulation order unchanged.
__global__ __launch_bounds__(256) void final_kernel(
        const bf16* __restrict__ f2, const float* __restrict__ glob,
        const bf16* __restrict__ atth,
        const float* __restrict__ out_w, const float* __restrict__ out_b,
        const float* __restrict__ r1_w, const float* __restrict__ r1_b,
        const float* __restrict__ r2_w, const float* __restrict__ r2_b,
        const float* __restrict__ r3_w, const float* __restrict__ r3_b,
        float* __restrict__ out) {
    const int bn0 = blockIdx.x * 8;
    const int b = bn0 >> 11;
    const int tid = threadIdx.x;
    __shared__ float attin[8][128], comb[8][384], h1[8][128], h2[8][64];
    __shared__ float logits[8][20], lse[8];

    for (int p = tid; p < 8 * 128; p += 256) {
        int rr = p >> 7, c = p & 127;
        attin[rr][c]      = b2f(atth[(size_t)(bn0 + rr) * 128 + c]);
        comb[rr][c]       = b2f(f2[(size_t)(bn0 + rr) * 128 + c]);
        comb[rr][128 + c] = glob[b * 128 + c];
    }
    __syncthreads();
    {
        const int col = tid & 127, r0 = (tid >> 7) * 4;
        float a0 = 0.f, a1 = 0.f, a2 = 0.f, a3 = 0.f;
        for (int c = 0; c < 128; ++c) {
            float wv = out_w[c * 128 + col];
            a0 += attin[r0 + 0][c] * wv; a1 += attin[r0 + 1][c] * wv;
            a2 += attin[r0 + 2][c] * wv; a3 += attin[r0 + 3][c] * wv;
        }
        float bb = out_b[col];
        comb[r0 + 0][256 + col] = a0 + bb; comb[r0 + 1][256 + col] = a1 + bb;
        comb[r0 + 2][256 + col] = a2 + bb; comb[r0 + 3][256 + col] = a3 + bb;
    }
    __syncthreads();
    {
        const int col = tid & 127, r0 = (tid >> 7) * 4;
        float a0 = 0.f, a1 = 0.f, a2 = 0.f, a3 = 0.f;
        for (int c = 0; c < 384; ++c) {
            float wv = r1_w[c * 128 + col];
            a0 += comb[r0 + 0][c] * wv; a1 += comb[r0 + 1][c] * wv;
            a2 += comb[r0 + 2][c] * wv; a3 += comb[r0 + 3][c] * wv;
        }
        float bb = r1_b[col];
        h1[r0 + 0][col] = fmaxf(a0 + bb, 0.f); h1[r0 + 1][col] = fmaxf(a1 + bb, 0.f);
        h1[r0 + 2][col] = fmaxf(a2 + bb, 0.f); h1[r0 + 3][col] = fmaxf(a3 + bb, 0.f);
    }
    __syncthreads();
    {
        const int col = tid & 63, r0 = (tid >> 6) * 2;   // 4 groups x 2 rows
        float a0 = 0.f, a1 = 0.f;
        for (int c = 0; c < 128; ++c) {
            float wv = r2_w[c * 64 + col];
            a0 += h1[r0 + 0][c] * wv; a1 += h1[r0 + 1][c] * wv;
        }
        float bb = r2_b[col];
        h2[r0 + 0][col] = fmaxf(a0 + bb, 0.f); h2[r0 + 1][col] = fmaxf(a1 + bb, 0.f);
    }
    __syncthreads();
    if (tid < 160) {
        const int cls = tid % 20, rr = tid / 20;         // 8 rows x 20 cols
        float a0 = 0.f;
        for (int c = 0; c < 64; ++c) a0 += h2[rr][c] * r3_w[c * 20 + cls];
        logits[rr][cls] = a0 + r3_b[cls];
    }
    __syncthreads();
    if (tid < 8) {
        float m = -INFINITY;
        for (int u = 0; u < 20; ++u) m = fmaxf(m, logits[tid][u]);
        float s = 0.f;
        for (int u = 0; u < 20; ++u) s += expf(logits[tid][u] - m);
        lse[tid] = m + logf(s);
    }
    __syncthreads();
    if (tid < 160) {
        int rr = tid / 20, cls = tid % 20;
        out[(size_t)(bn0 + rr) * 20 + cls] = logits[rr][cls] - lse[rr];
    }
}

// ----------------------------------------------------------------------------
// Layout (ws >= NEED_A = 16,846,848 B):
//   [0,4M)       f1T (phases 1-3) -> f2 bf16 (phase 3+)
//   [4M,+64K)    sqb | [4M+64K,8M+64K) f1 | [8M+64K,+640K) knn | +192K xT3
//   [4M,8M)      kkA (after ec2; f1/sqb dead) | [8M,12M) vtA
//   [12M,16M)    G (gemmG scratch, phases 1-3) -> atth (attention phase)
//   [16M,+68K)   pmax | glob
extern "C" void kernel_launch(void* const* d_in, const int* in_sizes, int n_in,
                              void* d_out, int out_size, void* d_ws, size_t ws_size,
                              hipStream_t stream) {
    const float* x      = (const float*)d_in[0];
    const float* ec1_w1 = (const float*)d_in[2];
    const float* ec1_b1 = (const float*)d_in[3];
    const float* ec1_w2 = (const float*)d_in[4];
    const float* ec1_b2 = (const float*)d_in[5];
    const float* ec2_w1 = (const float*)d_in[6];
    const float* ec2_b1 = (const float*)d_in[7];
    const float* ec2_w2 = (const float*)d_in[8];
    const float* ec2_b2 = (const float*)d_in[9];
    const float* qkv_w  = (const float*)d_in[10];
    const float* out_w  = (const float*)d_in[11];
    const float* out_b  = (const float*)d_in[12];
    const float* r1_w   = (const float*)d_in[13];
    const float* r1_b   = (const float*)d_in[14];
    const float* r2_w   = (const float*)d_in[15];
    const float* r2_b   = (const float*)d_in[16];
    const float* r3_w   = (const float*)d_in[17];
    const float* r3_b   = (const float*)d_in[18];
    float* out = (float*)d_out;

    const size_t MB = 1024 * 1024;
    const size_t NEED_A = 16 * MB + 65536 + 4096;
    if (ws_size < NEED_A) return;   // guard (clean numeric fail, not a fault)

    char* base = (char*)d_ws;
    bf16*  f2   = (bf16*)(base);
    float* f1T  = (float*)(base);
    float* sqb  = (float*)(base + 4 * MB);
    float* f1   = (float*)(base + 4 * MB + 65536);
    u16*   knn  = (u16*)(base + 8 * MB + 65536);
    float* xT3  = (float*)(base + 8 * MB + 65536 + 655360);
    float* G    = (float*)(base + 12 * MB);           // phases 1-3
    bf16*  kkA  = (bf16*)(base + 4 * MB);             // attention phase
    bf16*  vtA  = (bf16*)(base + 8 * MB);
    bf16*  atth = (bf16*)(base + 12 * MB);
    float* pmax = (float*)(base + 16 * MB);
    float* glob = (float*)(base + 16 * MB + 65536);

    sqT_kernel<3><<<BBNN / 256, 256, 0, stream>>>(x, sqb, xT3);
    knn1_kernel<3><<<BB * 256, 512, 0, stream>>>(x, xT3, sqb, knn);
    gemmG_kernel<3><<<BBNN / 16, 256, 0, stream>>>(x, ec1_w1, G);
    edgeconv3_kernel<3, 64, false><<<BBNN / 4, 256, 0, stream>>>(
        x, knn, ec1_w1, ec1_b1, ec1_w2, ec1_b2, G, f1);

    sqT_kernel<64><<<BBNN / 256, 256, 0, stream>>>(f1, sqb, f1T);
    knn_fast_kernel<64, 8><<<BB * 128, 512, 0, stream>>>(f1, f1T, sqb, knn);
    gemmG_kernel<64><<<BBNN / 16, 256, 0, stream>>>(f1, ec2_w1, G);
    edgeconv3_kernel<64, 128, true><<<BBNN / 4, 256, 0, stream>>>(
        f1, knn, ec2_w1, ec2_b1, ec2_w2, ec2_b2, G, f2);

    gmax1_kernel<<<BB * 16, 128, 0, stream>>>(f2, pmax);
    gmax2_kernel<<<BB, 128, 0, stream>>>(pmax, glob);

    kvt_kernel<<<4 * BBNN / 16, 256, 0, stream>>>(f2, qkv_w, kkA, vtA);
    attn_mfma_kernel<<<BB * 4 * 32, 256, 0, stream>>>(f2, qkv_w, kkA, vtA, atth);

    final_kernel<<<BBNN / 8, 256, 0, stream>>>(
        f2, glob, atth, out_w, out_b, r1_w, r1_b, r2_w, r2_b, r3_w, r3_b, out);
}